// Round 1
// baseline (824.498 us; speedup 1.0000x reference)
//
#include <hip/hip_runtime.h>
#include <math.h>

#define N_NODES 100000
#define N_EDGES 1600000
#define IN_DIM  256
#define HIDDEN  128

// ---------------- degree / sort kernels ----------------

__global__ void count_kernel(const int* __restrict__ col, int* __restrict__ cnt, int E) {
    int e = blockIdx.x * 256 + threadIdx.x;
    if (e < E) atomicAdd(&cnt[col[e]], 1);
}

// per-block exclusive scan of cnt -> offs, block sums -> partials
__global__ void scan1_kernel(const int* __restrict__ cnt, int* __restrict__ offs,
                             int* __restrict__ partials, int N) {
    __shared__ int s[256];
    int i = blockIdx.x * 256 + threadIdx.x;
    int v = (i < N) ? cnt[i] : 0;
    s[threadIdx.x] = v;
    __syncthreads();
    for (int d = 1; d < 256; d <<= 1) {
        int t = (threadIdx.x >= d) ? s[threadIdx.x - d] : 0;
        __syncthreads();
        s[threadIdx.x] += t;
        __syncthreads();
    }
    if (i < N) offs[i] = s[threadIdx.x] - v;            // exclusive
    if (threadIdx.x == 255) partials[blockIdx.x] = s[255];
}

// single block: exclusive scan of partials (NB <= 512)
__global__ void scan2_kernel(int* __restrict__ partials, int NB) {
    __shared__ int s[512];
    int v = (threadIdx.x < NB) ? partials[threadIdx.x] : 0;
    s[threadIdx.x] = v;
    __syncthreads();
    for (int d = 1; d < 512; d <<= 1) {
        int t = (threadIdx.x >= d) ? s[threadIdx.x - d] : 0;
        __syncthreads();
        s[threadIdx.x] += t;
        __syncthreads();
    }
    if (threadIdx.x < NB) partials[threadIdx.x] = s[threadIdx.x] - v;
}

// add block bases, init cursor, compute dinv = rsqrt(deg) with deg = cnt+1 (self loop)
__global__ void scan3_kernel(const int* __restrict__ cnt, int* __restrict__ offs,
                             const int* __restrict__ partials, int* __restrict__ cursor,
                             float* __restrict__ dinv, int N) {
    int i = blockIdx.x * 256 + threadIdx.x;
    if (i < N) {
        int o = offs[i] + partials[i >> 8];
        offs[i] = o;
        cursor[i] = o;
        dinv[i] = rsqrtf((float)(cnt[i] + 1));
    }
}

__global__ void scatter_kernel(const int* __restrict__ row, const int* __restrict__ col,
                               int* __restrict__ cursor, int* __restrict__ sortedRow, int E) {
    int e = blockIdx.x * 256 + threadIdx.x;
    if (e < E) {
        int c = col[e];
        int p = atomicAdd(&cursor[c], 1);
        sortedRow[p] = row[e];
    }
}

// ---------------- GEMM 1: t0[M,128] = x[M,256] @ W0[256,128] ----------------

__launch_bounds__(256)
__global__ void gemm1_kernel(const float* __restrict__ A, const float* __restrict__ B,
                             float* __restrict__ C) {
    __shared__ float As[64 * 36];   // [row][k] padded stride 36 (16B aligned)
    __shared__ float Bs[32 * 128];  // [k][col]
    const int tid = threadIdx.x;
    const int row0 = blockIdx.x * 64;
    const int mrow0 = (tid >> 5) * 8;   // 0..56
    const int cbase = (tid & 31) * 4;   // 0..124
    float acc[8][4] = {};

    for (int k0 = 0; k0 < 256; k0 += 32) {
        #pragma unroll
        for (int i = 0; i < 2; i++) {
            int f = tid + i * 256;
            int ar = f >> 3, kc4 = (f & 7) * 4;
            int gr = row0 + ar;
            float4 v = make_float4(0.f, 0.f, 0.f, 0.f);
            if (gr < N_NODES) v = *(const float4*)&A[gr * 256 + k0 + kc4];
            *(float4*)&As[ar * 36 + kc4] = v;
        }
        #pragma unroll
        for (int i = 0; i < 4; i++) {
            int f = tid + i * 256;
            int br = f >> 5, bc4 = (f & 31) * 4;
            *(float4*)&Bs[br * 128 + bc4] = *(const float4*)&B[(k0 + br) * 128 + bc4];
        }
        __syncthreads();
        #pragma unroll
        for (int kk = 0; kk < 32; kk += 4) {
            float4 a4[8];
            #pragma unroll
            for (int i = 0; i < 8; i++) a4[i] = *(float4*)&As[(mrow0 + i) * 36 + kk];
            #pragma unroll
            for (int q = 0; q < 4; q++) {
                float4 b = *(float4*)&Bs[(kk + q) * 128 + cbase];
                #pragma unroll
                for (int i = 0; i < 8; i++) {
                    float av = (q == 0) ? a4[i].x : (q == 1) ? a4[i].y : (q == 2) ? a4[i].z : a4[i].w;
                    acc[i][0] += av * b.x; acc[i][1] += av * b.y;
                    acc[i][2] += av * b.z; acc[i][3] += av * b.w;
                }
            }
        }
        __syncthreads();
    }
    #pragma unroll
    for (int i = 0; i < 8; i++) {
        int gr = row0 + mrow0 + i;
        if (gr < N_NODES)
            *(float4*)&C[gr * 128 + cbase] =
                make_float4(acc[i][0], acc[i][1], acc[i][2], acc[i][3]);
    }
}

// ---------------- aggregation: dst[n] = dinv[n]^2*src[n] + sum_e dinv[n]dinv[r]*src[r] ----------------
// EPI==1: dst = relu(agg + bias). One wave per node; lane owns features {lane, lane+64}.

template <int EPI>
__global__ void agg_kernel(const float* __restrict__ src, float* __restrict__ dst,
                           const int* __restrict__ offs, const int* __restrict__ cnt,
                           const int* __restrict__ sortedRow, const float* __restrict__ dinv,
                           const float* __restrict__ bias) {
    int n = blockIdx.x * 4 + (threadIdx.x >> 6);
    if (n >= N_NODES) return;
    int lane = threadIdx.x & 63;
    float dn = dinv[n];
    float acc0 = dn * dn * src[n * 128 + lane];
    float acc1 = dn * dn * src[n * 128 + 64 + lane];
    int start = offs[n], num = cnt[n];
    for (int i = 0; i < num; i++) {
        int r = sortedRow[start + i];
        float w = dn * dinv[r];
        acc0 += w * src[r * 128 + lane];
        acc1 += w * src[r * 128 + 64 + lane];
    }
    if (EPI == 1) {
        acc0 = fmaxf(acc0 + bias[lane], 0.f);
        acc1 = fmaxf(acc1 + bias[64 + lane], 0.f);
    }
    dst[n * 128 + lane] = acc0;
    dst[n * 128 + 64 + lane] = acc1;
}

// ---------------- GEMM 2 (fused mu & sigma): reads agg_h (aliases out lower half) ----------------
// Block owns rows [row0,row0+32): reads ONLY those agg_h rows, writes mu to the same
// rows (lower half) and sigma to upper half -> no cross-block hazard.

__launch_bounds__(256)
__global__ void gemm2_kernel(const float* A, const float* __restrict__ Wmu,
                             const float* __restrict__ Wsig, const float* __restrict__ bmu,
                             const float* __restrict__ bsig, float* out) {
    __shared__ float As[32 * 36];
    __shared__ float Bs[32 * 256];  // [k][ mu cols 0..127 | sigma cols 128..255 ]
    const int tid = threadIdx.x;
    const int row0 = blockIdx.x * 32;
    const int mrow0 = (tid >> 6) * 8;   // 0..24
    const int cbase = (tid & 63) * 4;   // 0..252
    float acc[8][4] = {};

    for (int k0 = 0; k0 < 128; k0 += 32) {
        {
            int f = tid;
            int ar = f >> 3, kc4 = (f & 7) * 4;
            *(float4*)&As[ar * 36 + kc4] = *(const float4*)&A[(row0 + ar) * 128 + k0 + kc4];
        }
        #pragma unroll
        for (int i = 0; i < 8; i++) {
            int f = tid + i * 256;
            int br = f >> 6, c4 = (f & 63) * 4;
            const float* Wsrc = (c4 < 128) ? &Wmu[(k0 + br) * 128 + c4]
                                           : &Wsig[(k0 + br) * 128 + (c4 - 128)];
            *(float4*)&Bs[br * 256 + c4] = *(const float4*)Wsrc;
        }
        __syncthreads();
        #pragma unroll
        for (int kk = 0; kk < 32; kk += 4) {
            float4 a4[8];
            #pragma unroll
            for (int i = 0; i < 8; i++) a4[i] = *(float4*)&As[(mrow0 + i) * 36 + kk];
            #pragma unroll
            for (int q = 0; q < 4; q++) {
                float4 b = *(float4*)&Bs[(kk + q) * 256 + cbase];
                #pragma unroll
                for (int i = 0; i < 8; i++) {
                    float av = (q == 0) ? a4[i].x : (q == 1) ? a4[i].y : (q == 2) ? a4[i].z : a4[i].w;
                    acc[i][0] += av * b.x; acc[i][1] += av * b.y;
                    acc[i][2] += av * b.z; acc[i][3] += av * b.w;
                }
            }
        }
        __syncthreads();
    }

    const bool isMu = (cbase < 128);
    const int c = isMu ? cbase : cbase - 128;
    #pragma unroll
    for (int i = 0; i < 8; i++) {
        int gr = row0 + mrow0 + i;
        if (isMu) {
            *(float4*)&out[gr * 128 + c] =
                make_float4(acc[i][0] + bmu[c], acc[i][1] + bmu[c + 1],
                            acc[i][2] + bmu[c + 2], acc[i][3] + bmu[c + 3]);
        } else {
            float t[4];
            #pragma unroll
            for (int j = 0; j < 4; j++) {
                float xv = acc[i][j] + bsig[c + j];
                t[j] = fmaxf(xv, 0.f) + log1pf(expf(-fabsf(xv))) + 1e-7f;
            }
            *(float4*)&out[(size_t)N_NODES * 128 + gr * 128 + c] =
                make_float4(t[0], t[1], t[2], t[3]);
        }
    }
}

// ---------------- launch ----------------

extern "C" void kernel_launch(void* const* d_in, const int* in_sizes, int n_in,
                              void* d_out, int out_size, void* d_ws, size_t ws_size,
                              hipStream_t stream) {
    const float* x    = (const float*)d_in[0];
    const int*   ei   = (const int*)d_in[1];
    const int*   row  = ei;              // sources
    const int*   col  = ei + N_EDGES;    // targets
    const float* W0   = (const float*)d_in[2];
    const float* b0   = (const float*)d_in[3];
    const float* Wmu  = (const float*)d_in[4];
    const float* bmu  = (const float*)d_in[5];
    const float* Wsig = (const float*)d_in[6];
    const float* bsig = (const float*)d_in[7];
    float* out = (float*)d_out;

    // workspace layout (~8 MB)
    int*   cnt       = (int*)d_ws;
    int*   offs      = cnt + N_NODES;
    int*   cursor    = offs + N_NODES;
    float* dinvp     = (float*)(cursor + N_NODES);
    int*   sortedRow = (int*)(dinvp + N_NODES);
    int*   partials  = sortedRow + N_EDGES;   // 512 ints

    // big tensors live in d_out: t0 = lower half, h = upper half, then
    // agg_h overwrites lower, final mu/sigma overwrite lower/upper.
    float* t0 = out;
    float* h  = out + (size_t)N_NODES * HIDDEN;

    const int NB = (N_NODES + 255) / 256;   // 391
    const int EB = (N_EDGES + 255) / 256;   // 6250

    hipMemsetAsync(cnt, 0, N_NODES * sizeof(int), stream);
    count_kernel<<<EB, 256, 0, stream>>>(col, cnt, N_EDGES);
    scan1_kernel<<<NB, 256, 0, stream>>>(cnt, offs, partials, N_NODES);
    scan2_kernel<<<1, 512, 0, stream>>>(partials, NB);
    scan3_kernel<<<NB, 256, 0, stream>>>(cnt, offs, partials, cursor, dinvp, N_NODES);
    scatter_kernel<<<EB, 256, 0, stream>>>(row, col, cursor, sortedRow, N_EDGES);

    gemm1_kernel<<<(N_NODES + 63) / 64, 256, 0, stream>>>(x, W0, t0);
    agg_kernel<1><<<N_NODES / 4, 256, 0, stream>>>(t0, h, offs, cnt, sortedRow, dinvp, b0);
    agg_kernel<0><<<N_NODES / 4, 256, 0, stream>>>(h, t0, offs, cnt, sortedRow, dinvp, nullptr);
    gemm2_kernel<<<N_NODES / 32, 256, 0, stream>>>(t0, Wmu, Wsig, bmu, bsig, out);
}

// Round 2
// 734.700 us; speedup vs baseline: 1.1222x; 1.1222x over previous
//
#include <hip/hip_runtime.h>
#include <math.h>

#define N_NODES 100000
#define N_EDGES 1600000
#define ROWB    512                 // bytes per row slot in d_out
#define HALFB   51200000ull         // byte offset of second output (sigma half)

typedef float  f32x4  __attribute__((ext_vector_type(4)));
typedef __bf16 bf16x8 __attribute__((ext_vector_type(8)));
typedef short  s16x8  __attribute__((ext_vector_type(8)));

__device__ __forceinline__ unsigned short f2bf(float f) {
    unsigned int u = __builtin_bit_cast(unsigned int, f);
    u += 0x7FFFu + ((u >> 16) & 1u);          // RNE
    return (unsigned short)(u >> 16);
}
__device__ __forceinline__ float bf2f(unsigned short h) {
    unsigned int u = ((unsigned int)h) << 16;
    return __builtin_bit_cast(float, u);
}

#define MFMA16(a, b, c) __builtin_amdgcn_mfma_f32_16x16x32_bf16((a), (b), (c), 0, 0, 0)

// ---------------- degree / counting-sort kernels ----------------

__global__ void count_kernel(const int* __restrict__ col, int* __restrict__ cnt, int E) {
    int e = blockIdx.x * 256 + threadIdx.x;
    if (e < E) atomicAdd(&cnt[col[e]], 1);
}

__global__ void scan1_kernel(const int* __restrict__ cnt, int* __restrict__ offs,
                             int* __restrict__ partials, int N) {
    __shared__ int s[256];
    int i = blockIdx.x * 256 + threadIdx.x;
    int v = (i < N) ? cnt[i] : 0;
    s[threadIdx.x] = v;
    __syncthreads();
    for (int d = 1; d < 256; d <<= 1) {
        int t = (threadIdx.x >= d) ? s[threadIdx.x - d] : 0;
        __syncthreads();
        s[threadIdx.x] += t;
        __syncthreads();
    }
    if (i < N) offs[i] = s[threadIdx.x] - v;
    if (threadIdx.x == 255) partials[blockIdx.x] = s[255];
}

__global__ void scan2_kernel(int* __restrict__ partials, int NB) {
    __shared__ int s[512];
    int v = (threadIdx.x < NB) ? partials[threadIdx.x] : 0;
    s[threadIdx.x] = v;
    __syncthreads();
    for (int d = 1; d < 512; d <<= 1) {
        int t = (threadIdx.x >= d) ? s[threadIdx.x - d] : 0;
        __syncthreads();
        s[threadIdx.x] += t;
        __syncthreads();
    }
    if (threadIdx.x < NB) partials[threadIdx.x] = s[threadIdx.x] - v;
}

__global__ void scan3_kernel(const int* __restrict__ cnt, int* __restrict__ offs,
                             const int* __restrict__ partials, int* __restrict__ cursor,
                             float* __restrict__ dinv, int N) {
    int i = blockIdx.x * 256 + threadIdx.x;
    if (i < N) {
        int o = offs[i] + partials[i >> 8];
        offs[i] = o;
        cursor[i] = o;
        dinv[i] = rsqrtf((float)(cnt[i] + 1));   // +1 self loop
    }
}

__global__ void scatter_kernel(const int* __restrict__ row, const int* __restrict__ col,
                               int* __restrict__ cursor, int* __restrict__ sortedRow, int E) {
    int e = blockIdx.x * 256 + threadIdx.x;
    if (e < E) {
        int c = col[e];
        int p = atomicAdd(&cursor[c], 1);
        sortedRow[p] = row[e];
    }
}

// ---------------- weight pre-transpose (fp32 -> bf16 hi/lo, fragment layout [col][k]) ----

__global__ void prep_w(const float* __restrict__ W0, const float* __restrict__ Wmu,
                       const float* __restrict__ Wsig,
                       unsigned short* __restrict__ W0h, unsigned short* __restrict__ W0l,
                       unsigned short* __restrict__ Wmsh, unsigned short* __restrict__ Wmsl) {
    int c = blockIdx.x;
    int k = threadIdx.x;
    if (c < 128) {                               // W0 [256][128] -> [128 cols][256 k]
        float v = W0[k * 128 + c];
        unsigned short h = f2bf(v);
        W0h[c * 256 + k] = h;
        W0l[c * 256 + k] = f2bf(v - bf2f(h));
    } else if (k < 128) {                        // Wmu|Wsig -> [256 cols][128 k]
        int c2 = c - 128;
        float v = (c2 < 128) ? Wmu[k * 128 + c2] : Wsig[k * 128 + (c2 - 128)];
        unsigned short h = f2bf(v);
        Wmsh[c2 * 128 + k] = h;
        Wmsl[c2 * 128 + k] = f2bf(v - bf2f(h));
    }
}

// ---------------- GEMM1: t0_bf16 = x[100k,256] @ W0[256,128] (3-term compensated) ----------

__launch_bounds__(256)
__global__ void gemm1_mfma(const float* __restrict__ x,
                           const unsigned short* __restrict__ Bh,
                           const unsigned short* __restrict__ Bl,
                           char* __restrict__ outc) {
    const int tid = threadIdx.x;
    const int wave = tid >> 6, lane = tid & 63;
    const int lrow = lane & 15, lk8 = (lane >> 4) * 8;
    const int r0 = blockIdx.x * 128 + wave * 32;

    f32x4 acc[2][8] = {};
    const float* ap[2];
    #pragma unroll
    for (int m = 0; m < 2; m++) {
        int rm = r0 + m * 16 + lrow;
        if (rm > N_NODES - 1) rm = N_NODES - 1;
        ap[m] = x + (size_t)rm * 256 + lk8;
    }
    for (int k0 = 0; k0 < 256; k0 += 32) {
        bf16x8 ah[2], al[2];
        #pragma unroll
        for (int m = 0; m < 2; m++) {
            float4 v0 = *(const float4*)(ap[m] + k0);
            float4 v1 = *(const float4*)(ap[m] + k0 + 4);
            float a[8] = {v0.x, v0.y, v0.z, v0.w, v1.x, v1.y, v1.z, v1.w};
            s16x8 hh, ll;
            #pragma unroll
            for (int j = 0; j < 8; j++) {
                unsigned short hb = f2bf(a[j]);
                hh[j] = (short)hb;
                ll[j] = (short)f2bf(a[j] - bf2f(hb));
            }
            ah[m] = __builtin_bit_cast(bf16x8, hh);
            al[m] = __builtin_bit_cast(bf16x8, ll);
        }
        #pragma unroll
        for (int n = 0; n < 8; n++) {
            const size_t bo = (size_t)(n * 16 + lrow) * 256 + k0 + lk8;
            bf16x8 bh = *(const bf16x8*)(Bh + bo);
            acc[0][n] = MFMA16(ah[0], bh, acc[0][n]);
            acc[1][n] = MFMA16(ah[1], bh, acc[1][n]);
            acc[0][n] = MFMA16(al[0], bh, acc[0][n]);
            acc[1][n] = MFMA16(al[1], bh, acc[1][n]);
            bf16x8 bl = *(const bf16x8*)(Bl + bo);
            acc[0][n] = MFMA16(ah[0], bl, acc[0][n]);
            acc[1][n] = MFMA16(ah[1], bl, acc[1][n]);
        }
    }
    // t0 row r lives at outc + r*512 + 256 (128 bf16)
    #pragma unroll
    for (int m = 0; m < 2; m++)
        #pragma unroll
        for (int n = 0; n < 8; n++) {
            int colb = 256 + (n * 16 + lrow) * 2;
            #pragma unroll
            for (int q = 0; q < 4; q++) {
                int row = r0 + m * 16 + (lane >> 4) * 4 + q;
                if (row < N_NODES)
                    *(unsigned short*)(outc + (size_t)row * ROWB + colb) = f2bf(acc[m][n][q]);
            }
        }
}

// ---------------- aggregation over bf16 rows (512B-strided), fp32 accumulate ------------

template <int EPI>
__launch_bounds__(256)
__global__ void agg_bf16(const char* __restrict__ srcBase, char* __restrict__ dstBase,
                         const int* __restrict__ offs, const int* __restrict__ cnt,
                         const int* __restrict__ sortedRow, const float* __restrict__ dinv,
                         const float* __restrict__ bias) {
    const int n = blockIdx.x * 4 + (threadIdx.x >> 6);
    const int lane = threadIdx.x & 63;
    const float dn = dinv[n];
    unsigned int u = *(const unsigned int*)(srcBase + (size_t)n * ROWB + lane * 4);
    const float ws = dn * dn;
    float acc0 = ws * bf2f((unsigned short)(u & 0xFFFF));
    float acc1 = ws * bf2f((unsigned short)(u >> 16));
    const int start = offs[n], num = cnt[n];
    for (int i = 0; i < num; i++) {
        int r = sortedRow[start + i];
        float w = dn * dinv[r];
        unsigned int ue = *(const unsigned int*)(srcBase + (size_t)r * ROWB + lane * 4);
        acc0 += w * bf2f((unsigned short)(ue & 0xFFFF));
        acc1 += w * bf2f((unsigned short)(ue >> 16));
    }
    if (EPI) {
        acc0 = fmaxf(acc0 + bias[2 * lane], 0.f);
        acc1 = fmaxf(acc1 + bias[2 * lane + 1], 0.f);
    }
    unsigned int o = (unsigned int)f2bf(acc0) | ((unsigned int)f2bf(acc1) << 16);
    *(unsigned int*)(dstBase + (size_t)n * ROWB + lane * 4) = o;
}

// ---------------- GEMM2: [mu|sigma] = t2_bf16[100k,128] @ [Wmu|Wsig] (2-term) -----------
// t2 row r aliases the first 256B of mu row r's slot; barrier before epilogue.

__launch_bounds__(256)
__global__ void gemm2_mfma(const unsigned short* __restrict__ Bh,
                           const unsigned short* __restrict__ Bl,
                           const float* __restrict__ bmu, const float* __restrict__ bsig,
                           char* __restrict__ outc) {
    const int tid = threadIdx.x;
    const int wave = tid >> 6, lane = tid & 63;
    const int rg = wave >> 1, ch = wave & 1;
    const int lrow = lane & 15, lk8 = (lane >> 4) * 8;
    const int r0 = blockIdx.x * 64 + rg * 32;

    f32x4 acc[2][8] = {};
    const char* apc[2];
    #pragma unroll
    for (int m = 0; m < 2; m++) {
        int rm = r0 + m * 16 + lrow;
        if (rm > N_NODES - 1) rm = N_NODES - 1;
        apc[m] = outc + (size_t)rm * ROWB + lk8 * 2;
    }
    #pragma unroll
    for (int k0 = 0; k0 < 128; k0 += 32) {
        bf16x8 a0 = *(const bf16x8*)(apc[0] + k0 * 2);
        bf16x8 a1 = *(const bf16x8*)(apc[1] + k0 * 2);
        #pragma unroll
        for (int n = 0; n < 8; n++) {
            const size_t bo = (size_t)(ch * 128 + n * 16 + lrow) * 128 + k0 + lk8;
            bf16x8 bh = *(const bf16x8*)(Bh + bo);
            acc[0][n] = MFMA16(a0, bh, acc[0][n]);
            acc[1][n] = MFMA16(a1, bh, acc[1][n]);
            bf16x8 bl = *(const bf16x8*)(Bl + bo);
            acc[0][n] = MFMA16(a0, bl, acc[0][n]);
            acc[1][n] = MFMA16(a1, bl, acc[1][n]);
        }
    }
    __syncthreads();   // all t2 reads of this block done before mu overwrites them
    #pragma unroll
    for (int n = 0; n < 8; n++) {
        int c = n * 16 + lrow;                  // 0..127 within half
        float bv = (ch == 0) ? bmu[c] : bsig[c];
        #pragma unroll
        for (int m = 0; m < 2; m++) {
            f32x4 v = acc[m][n];
            #pragma unroll
            for (int q = 0; q < 4; q++) {
                int row = r0 + m * 16 + (lane >> 4) * 4 + q;
                if (row >= N_NODES) continue;
                float val = v[q] + bv;
                if (ch == 0) {
                    *(float*)(outc + (size_t)row * ROWB + c * 4) = val;
                } else {
                    float sp = fmaxf(val, 0.f) + log1pf(expf(-fabsf(val))) + 1e-7f;
                    *(float*)(outc + HALFB + (size_t)row * ROWB + c * 4) = sp;
                }
            }
        }
    }
}

// ---------------- launch ----------------

extern "C" void kernel_launch(void* const* d_in, const int* in_sizes, int n_in,
                              void* d_out, int out_size, void* d_ws, size_t ws_size,
                              hipStream_t stream) {
    const float* x    = (const float*)d_in[0];
    const int*   ei   = (const int*)d_in[1];
    const int*   row  = ei;
    const int*   col  = ei + N_EDGES;
    const float* W0   = (const float*)d_in[2];
    const float* b0   = (const float*)d_in[3];
    const float* Wmu  = (const float*)d_in[4];
    const float* bmu  = (const float*)d_in[5];
    const float* Wsig = (const float*)d_in[6];
    const float* bsig = (const float*)d_in[7];
    char* outc = (char*)d_out;

    // workspace: weight transposes first (16B aligned), then sort arrays (~8.3MB)
    unsigned short* W0h  = (unsigned short*)d_ws;       // 128*256
    unsigned short* W0l  = W0h + 32768;
    unsigned short* Wmsh = W0l + 32768;                 // 256*128
    unsigned short* Wmsl = Wmsh + 32768;
    int*   cnt       = (int*)(Wmsl + 32768);
    int*   offs      = cnt + N_NODES;
    int*   cursor    = offs + N_NODES;
    float* dinvp     = (float*)(cursor + N_NODES);
    int*   sortedRow = (int*)(dinvp + N_NODES);
    int*   partials  = sortedRow + N_EDGES;             // 512 ints

    const int NB = (N_NODES + 255) / 256;               // 391
    const int EB = (N_EDGES + 255) / 256;               // 6250

    hipMemsetAsync(cnt, 0, N_NODES * sizeof(int), stream);
    count_kernel<<<EB, 256, 0, stream>>>(col, cnt, N_EDGES);
    scan1_kernel<<<NB, 256, 0, stream>>>(cnt, offs, partials, N_NODES);
    scan2_kernel<<<1, 512, 0, stream>>>(partials, NB);
    scan3_kernel<<<NB, 256, 0, stream>>>(cnt, offs, partials, cursor, dinvp, N_NODES);
    scatter_kernel<<<EB, 256, 0, stream>>>(row, col, cursor, sortedRow, N_EDGES);
    prep_w<<<384, 256, 0, stream>>>(W0, Wmu, Wsig, W0h, W0l, Wmsh, Wmsl);

    gemm1_mfma<<<(N_NODES + 127) / 128, 256, 0, stream>>>(x, W0h, W0l, outc);
    // t0 (+256 in mu slots) -> h (sigma slots)
    agg_bf16<1><<<N_NODES / 4, 256, 0, stream>>>(outc + 256, outc + HALFB,
                                                 offs, cnt, sortedRow, dinvp, b0);
    // h -> t2 (+0 in mu slots)
    agg_bf16<0><<<N_NODES / 4, 256, 0, stream>>>(outc + HALFB, outc,
                                                 offs, cnt, sortedRow, dinvp, nullptr);
    gemm2_mfma<<<(N_NODES + 63) / 64, 256, 0, stream>>>(Wmsh, Wmsl, bmu, bsig, outc);
}

// Round 3
// 557.690 us; speedup vs baseline: 1.4784x; 1.3174x over previous
//
#include <hip/hip_runtime.h>
#include <math.h>

#define N_NODES 100000
#define N_EDGES 1600000
#define ROWB    512                 // bytes per row slot in d_out
#define HALFB   51200000ull         // byte offset of second output (sigma half)

typedef float  f32x4  __attribute__((ext_vector_type(4)));
typedef __bf16 bf16x8 __attribute__((ext_vector_type(8)));
typedef short  s16x8  __attribute__((ext_vector_type(8)));

__device__ __forceinline__ unsigned short f2bf(float f) {
    unsigned int u = __builtin_bit_cast(unsigned int, f);
    u += 0x7FFFu + ((u >> 16) & 1u);          // RNE
    return (unsigned short)(u >> 16);
}
__device__ __forceinline__ float bf2f(unsigned short h) {
    unsigned int u = ((unsigned int)h) << 16;
    return __builtin_bit_cast(float, u);
}
__device__ __forceinline__ float bf_lo(unsigned int u) {
    return __builtin_bit_cast(float, u << 16);
}
__device__ __forceinline__ float bf_hi(unsigned int u) {
    return __builtin_bit_cast(float, u & 0xFFFF0000u);
}

#define MFMA16(a, b, c) __builtin_amdgcn_mfma_f32_16x16x32_bf16((a), (b), (c), 0, 0, 0)

// ---------------- degree / counting-sort kernels ----------------

__global__ void count_kernel(const int* __restrict__ col, int* __restrict__ cnt, int E) {
    int e = blockIdx.x * 256 + threadIdx.x;
    if (e < E) atomicAdd(&cnt[col[e]], 1);
}

__global__ void scan1_kernel(const int* __restrict__ cnt, int* __restrict__ offs,
                             int* __restrict__ partials, int N) {
    __shared__ int s[256];
    int i = blockIdx.x * 256 + threadIdx.x;
    int v = (i < N) ? cnt[i] : 0;
    s[threadIdx.x] = v;
    __syncthreads();
    for (int d = 1; d < 256; d <<= 1) {
        int t = (threadIdx.x >= d) ? s[threadIdx.x - d] : 0;
        __syncthreads();
        s[threadIdx.x] += t;
        __syncthreads();
    }
    if (i < N) offs[i] = s[threadIdx.x] - v;
    if (threadIdx.x == 255) partials[blockIdx.x] = s[255];
}

__global__ void scan2_kernel(int* __restrict__ partials, int NB) {
    __shared__ int s[512];
    int v = (threadIdx.x < NB) ? partials[threadIdx.x] : 0;
    s[threadIdx.x] = v;
    __syncthreads();
    for (int d = 1; d < 512; d <<= 1) {
        int t = (threadIdx.x >= d) ? s[threadIdx.x - d] : 0;
        __syncthreads();
        s[threadIdx.x] += t;
        __syncthreads();
    }
    if (threadIdx.x < NB) partials[threadIdx.x] = s[threadIdx.x] - v;
}

__global__ void scan3_kernel(const int* __restrict__ cnt, int* __restrict__ offs,
                             const int* __restrict__ partials, int* __restrict__ cursor,
                             float* __restrict__ dinv, int N) {
    int i = blockIdx.x * 256 + threadIdx.x;
    if (i < N) {
        int o = offs[i] + partials[i >> 8];
        offs[i] = o;
        cursor[i] = o;
        dinv[i] = rsqrtf((float)(cnt[i] + 1));   // +1 self loop
    }
}

__global__ void scatter_kernel(const int* __restrict__ row, const int* __restrict__ col,
                               int* __restrict__ cursor, int* __restrict__ sortedRow, int E) {
    int e = blockIdx.x * 256 + threadIdx.x;
    if (e < E) {
        int c = col[e];
        int p = atomicAdd(&cursor[c], 1);
        sortedRow[p] = row[e];
    }
}

// ---------------- weight pre-transpose (fp32 -> bf16 hi/lo, fragment layout [col][k]) ----

__global__ void prep_w(const float* __restrict__ W0, const float* __restrict__ Wmu,
                       const float* __restrict__ Wsig,
                       unsigned short* __restrict__ W0h, unsigned short* __restrict__ W0l,
                       unsigned short* __restrict__ Wmsh, unsigned short* __restrict__ Wmsl) {
    int c = blockIdx.x;
    int k = threadIdx.x;
    if (c < 128) {                               // W0 [256][128] -> [128 cols][256 k]
        float v = W0[k * 128 + c];
        unsigned short h = f2bf(v);
        W0h[c * 256 + k] = h;
        W0l[c * 256 + k] = f2bf(v - bf2f(h));
    } else if (k < 128) {                        // Wmu|Wsig -> [256 cols][128 k]
        int c2 = c - 128;
        float v = (c2 < 128) ? Wmu[k * 128 + c2] : Wsig[k * 128 + (c2 - 128)];
        unsigned short h = f2bf(v);
        Wmsh[c2 * 128 + k] = h;
        Wmsl[c2 * 128 + k] = f2bf(v - bf2f(h));
    }
}

// ---------------- GEMM1: t0_bf16 = x[100k,256] @ W0[256,128] (3-term compensated) ----------

__launch_bounds__(256)
__global__ void gemm1_mfma(const float* __restrict__ x,
                           const unsigned short* __restrict__ Bh,
                           const unsigned short* __restrict__ Bl,
                           char* __restrict__ outc) {
    const int tid = threadIdx.x;
    const int wave = tid >> 6, lane = tid & 63;
    const int lrow = lane & 15, lk8 = (lane >> 4) * 8;
    const int r0 = blockIdx.x * 128 + wave * 32;

    f32x4 acc[2][8] = {};
    const float* ap[2];
    #pragma unroll
    for (int m = 0; m < 2; m++) {
        int rm = r0 + m * 16 + lrow;
        if (rm > N_NODES - 1) rm = N_NODES - 1;
        ap[m] = x + (size_t)rm * 256 + lk8;
    }
    for (int k0 = 0; k0 < 256; k0 += 32) {
        bf16x8 ah[2], al[2];
        #pragma unroll
        for (int m = 0; m < 2; m++) {
            float4 v0 = *(const float4*)(ap[m] + k0);
            float4 v1 = *(const float4*)(ap[m] + k0 + 4);
            float a[8] = {v0.x, v0.y, v0.z, v0.w, v1.x, v1.y, v1.z, v1.w};
            s16x8 hh, ll;
            #pragma unroll
            for (int j = 0; j < 8; j++) {
                unsigned short hb = f2bf(a[j]);
                hh[j] = (short)hb;
                ll[j] = (short)f2bf(a[j] - bf2f(hb));
            }
            ah[m] = __builtin_bit_cast(bf16x8, hh);
            al[m] = __builtin_bit_cast(bf16x8, ll);
        }
        #pragma unroll
        for (int n = 0; n < 8; n++) {
            const size_t bo = (size_t)(n * 16 + lrow) * 256 + k0 + lk8;
            bf16x8 bh = *(const bf16x8*)(Bh + bo);
            acc[0][n] = MFMA16(ah[0], bh, acc[0][n]);
            acc[1][n] = MFMA16(ah[1], bh, acc[1][n]);
            acc[0][n] = MFMA16(al[0], bh, acc[0][n]);
            acc[1][n] = MFMA16(al[1], bh, acc[1][n]);
            bf16x8 bl = *(const bf16x8*)(Bl + bo);
            acc[0][n] = MFMA16(ah[0], bl, acc[0][n]);
            acc[1][n] = MFMA16(ah[1], bl, acc[1][n]);
        }
    }
    // t0 row r lives at outc + r*512 + 256 (128 bf16)
    #pragma unroll
    for (int m = 0; m < 2; m++)
        #pragma unroll
        for (int n = 0; n < 8; n++) {
            int colb = 256 + (n * 16 + lrow) * 2;
            #pragma unroll
            for (int q = 0; q < 4; q++) {
                int row = r0 + m * 16 + (lane >> 4) * 4 + q;
                if (row < N_NODES)
                    *(unsigned short*)(outc + (size_t)row * ROWB + colb) = f2bf(acc[m][n][q]);
            }
        }
}

// ---------------- aggregation over bf16 rows (512B-strided), fp32 accumulate ------------
// 8-wide predicated edge batches: 8 independent row gathers in flight per wave.
// Invalid tail slots gather row n (L1-hit) with weight 0 -> no wasted HBM traffic.

template <int EPI>
__launch_bounds__(256)
__global__ void agg_bf16(const char* __restrict__ srcBase, char* __restrict__ dstBase,
                         const int* __restrict__ offs, const int* __restrict__ cnt,
                         const int* __restrict__ sortedRow, const float* __restrict__ dinv,
                         const float* __restrict__ bias) {
    const int n = blockIdx.x * 4 + (threadIdx.x >> 6);
    const int lane = threadIdx.x & 63;
    const float dn = dinv[n];
    const char* srcLane = srcBase + (size_t)lane * 4;
    unsigned int u = *(const unsigned int*)(srcLane + (size_t)n * ROWB);
    const float ws = dn * dn;
    float acc0 = ws * bf_lo(u);
    float acc1 = ws * bf_hi(u);
    const int start = offs[n], num = cnt[n];

    for (int i = 0; i < num; i += 8) {
        int r[8];
        #pragma unroll
        for (int j = 0; j < 8; j++) {
            bool valid = (i + j) < num;
            int idx = start + (valid ? (i + j) : 0);
            int rr = sortedRow[idx];
            r[j] = valid ? rr : n;
        }
        unsigned int ue[8];
        #pragma unroll
        for (int j = 0; j < 8; j++)
            ue[j] = *(const unsigned int*)(srcLane + (size_t)r[j] * ROWB);
        float w[8];
        #pragma unroll
        for (int j = 0; j < 8; j++) {
            float wv = dn * dinv[r[j]];
            w[j] = ((i + j) < num) ? wv : 0.f;
        }
        #pragma unroll
        for (int j = 0; j < 8; j++) {
            acc0 = fmaf(w[j], bf_lo(ue[j]), acc0);
            acc1 = fmaf(w[j], bf_hi(ue[j]), acc1);
        }
    }

    if (EPI) {
        acc0 = fmaxf(acc0 + bias[2 * lane], 0.f);
        acc1 = fmaxf(acc1 + bias[2 * lane + 1], 0.f);
    }
    unsigned int o = (unsigned int)f2bf(acc0) | ((unsigned int)f2bf(acc1) << 16);
    *(unsigned int*)(dstBase + (size_t)n * ROWB + lane * 4) = o;
}

// ---------------- GEMM2: [mu|sigma] = t2_bf16[100k,128] @ [Wmu|Wsig] (2-term) -----------
// t2 row r aliases the first 256B of mu row r's slot; barrier before epilogue.

__launch_bounds__(256)
__global__ void gemm2_mfma(const unsigned short* __restrict__ Bh,
                           const unsigned short* __restrict__ Bl,
                           const float* __restrict__ bmu, const float* __restrict__ bsig,
                           char* __restrict__ outc) {
    const int tid = threadIdx.x;
    const int wave = tid >> 6, lane = tid & 63;
    const int rg = wave >> 1, ch = wave & 1;
    const int lrow = lane & 15, lk8 = (lane >> 4) * 8;
    const int r0 = blockIdx.x * 64 + rg * 32;

    f32x4 acc[2][8] = {};
    const char* apc[2];
    #pragma unroll
    for (int m = 0; m < 2; m++) {
        int rm = r0 + m * 16 + lrow;
        if (rm > N_NODES - 1) rm = N_NODES - 1;
        apc[m] = outc + (size_t)rm * ROWB + lk8 * 2;
    }
    #pragma unroll
    for (int k0 = 0; k0 < 128; k0 += 32) {
        bf16x8 a0 = *(const bf16x8*)(apc[0] + k0 * 2);
        bf16x8 a1 = *(const bf16x8*)(apc[1] + k0 * 2);
        #pragma unroll
        for (int n = 0; n < 8; n++) {
            const size_t bo = (size_t)(ch * 128 + n * 16 + lrow) * 128 + k0 + lk8;
            bf16x8 bh = *(const bf16x8*)(Bh + bo);
            acc[0][n] = MFMA16(a0, bh, acc[0][n]);
            acc[1][n] = MFMA16(a1, bh, acc[1][n]);
            bf16x8 bl = *(const bf16x8*)(Bl + bo);
            acc[0][n] = MFMA16(a0, bl, acc[0][n]);
            acc[1][n] = MFMA16(a1, bl, acc[1][n]);
        }
    }
    __syncthreads();   // all t2 reads of this block done before mu overwrites them
    #pragma unroll
    for (int n = 0; n < 8; n++) {
        int c = n * 16 + lrow;                  // 0..127 within half
        float bv = (ch == 0) ? bmu[c] : bsig[c];
        #pragma unroll
        for (int m = 0; m < 2; m++) {
            f32x4 v = acc[m][n];
            #pragma unroll
            for (int q = 0; q < 4; q++) {
                int row = r0 + m * 16 + (lane >> 4) * 4 + q;
                if (row >= N_NODES) continue;
                float val = v[q] + bv;
                if (ch == 0) {
                    *(float*)(outc + (size_t)row * ROWB + c * 4) = val;
                } else {
                    float sp = fmaxf(val, 0.f) + log1pf(expf(-fabsf(val))) + 1e-7f;
                    *(float*)(outc + HALFB + (size_t)row * ROWB + c * 4) = sp;
                }
            }
        }
    }
}

// ---------------- launch ----------------

extern "C" void kernel_launch(void* const* d_in, const int* in_sizes, int n_in,
                              void* d_out, int out_size, void* d_ws, size_t ws_size,
                              hipStream_t stream) {
    const float* x    = (const float*)d_in[0];
    const int*   ei   = (const int*)d_in[1];
    const int*   row  = ei;
    const int*   col  = ei + N_EDGES;
    const float* W0   = (const float*)d_in[2];
    const float* b0   = (const float*)d_in[3];
    const float* Wmu  = (const float*)d_in[4];
    const float* bmu  = (const float*)d_in[5];
    const float* Wsig = (const float*)d_in[6];
    const float* bsig = (const float*)d_in[7];
    char* outc = (char*)d_out;

    // workspace: weight transposes first (16B aligned), then sort arrays (~8.3MB)
    unsigned short* W0h  = (unsigned short*)d_ws;       // 128*256
    unsigned short* W0l  = W0h + 32768;
    unsigned short* Wmsh = W0l + 32768;                 // 256*128
    unsigned short* Wmsl = Wmsh + 32768;
    int*   cnt       = (int*)(Wmsl + 32768);
    int*   offs      = cnt + N_NODES;
    int*   cursor    = offs + N_NODES;
    float* dinvp     = (float*)(cursor + N_NODES);
    int*   sortedRow = (int*)(dinvp + N_NODES);
    int*   partials  = sortedRow + N_EDGES;             // 512 ints

    const int NB = (N_NODES + 255) / 256;               // 391
    const int EB = (N_EDGES + 255) / 256;               // 6250

    hipMemsetAsync(cnt, 0, N_NODES * sizeof(int), stream);
    count_kernel<<<EB, 256, 0, stream>>>(col, cnt, N_EDGES);
    scan1_kernel<<<NB, 256, 0, stream>>>(cnt, offs, partials, N_NODES);
    scan2_kernel<<<1, 512, 0, stream>>>(partials, NB);
    scan3_kernel<<<NB, 256, 0, stream>>>(cnt, offs, partials, cursor, dinvp, N_NODES);
    scatter_kernel<<<EB, 256, 0, stream>>>(row, col, cursor, sortedRow, N_EDGES);
    prep_w<<<384, 256, 0, stream>>>(W0, Wmu, Wsig, W0h, W0l, Wmsh, Wmsl);

    gemm1_mfma<<<(N_NODES + 127) / 128, 256, 0, stream>>>(x, W0h, W0l, outc);
    // t0 (+256 in mu slots) -> h (sigma slots)
    agg_bf16<1><<<N_NODES / 4, 256, 0, stream>>>(outc + 256, outc + HALFB,
                                                 offs, cnt, sortedRow, dinvp, b0);
    // h -> t2 (+0 in mu slots)
    agg_bf16<0><<<N_NODES / 4, 256, 0, stream>>>(outc + HALFB, outc,
                                                 offs, cnt, sortedRow, dinvp, nullptr);
    gemm2_mfma<<<(N_NODES + 63) / 64, 256, 0, stream>>>(Wmsh, Wmsl, bmu, bsig, outc);
}

// Round 4
// 496.435 us; speedup vs baseline: 1.6608x; 1.1234x over previous
//
#include <hip/hip_runtime.h>
#include <math.h>

#define N_NODES 100000
#define N_EDGES 1600000
#define ROWB    512                 // bytes per row slot in d_out
#define HALFB   51200000ull         // byte offset of second output (sigma half)

typedef float  f32x4  __attribute__((ext_vector_type(4)));
typedef __bf16 bf16x8 __attribute__((ext_vector_type(8)));
typedef short  s16x8  __attribute__((ext_vector_type(8)));

__device__ __forceinline__ unsigned short f2bf(float f) {
    unsigned int u = __builtin_bit_cast(unsigned int, f);
    u += 0x7FFFu + ((u >> 16) & 1u);          // RNE
    return (unsigned short)(u >> 16);
}
__device__ __forceinline__ float bf2f(unsigned short h) {
    unsigned int u = ((unsigned int)h) << 16;
    return __builtin_bit_cast(float, u);
}
__device__ __forceinline__ float bf_lo(unsigned int u) {
    return __builtin_bit_cast(float, u << 16);
}
__device__ __forceinline__ float bf_hi(unsigned int u) {
    return __builtin_bit_cast(float, u & 0xFFFF0000u);
}

#define MFMA16(a, b, c) __builtin_amdgcn_mfma_f32_16x16x32_bf16((a), (b), (c), 0, 0, 0)

// ---------------- degree / counting-sort kernels ----------------

__global__ void count_kernel(const int* __restrict__ col, int* __restrict__ cnt, int E) {
    int e = blockIdx.x * 256 + threadIdx.x;
    if (e < E) atomicAdd(&cnt[col[e]], 1);
}

__global__ void scan1_kernel(const int* __restrict__ cnt, int* __restrict__ offs,
                             int* __restrict__ partials, int N) {
    __shared__ int s[256];
    int i = blockIdx.x * 256 + threadIdx.x;
    int v = (i < N) ? cnt[i] : 0;
    s[threadIdx.x] = v;
    __syncthreads();
    for (int d = 1; d < 256; d <<= 1) {
        int t = (threadIdx.x >= d) ? s[threadIdx.x - d] : 0;
        __syncthreads();
        s[threadIdx.x] += t;
        __syncthreads();
    }
    if (i < N) offs[i] = s[threadIdx.x] - v;
    if (threadIdx.x == 255) partials[blockIdx.x] = s[255];
}

__global__ void scan2_kernel(int* __restrict__ partials, int NB) {
    __shared__ int s[512];
    int v = (threadIdx.x < NB) ? partials[threadIdx.x] : 0;
    s[threadIdx.x] = v;
    __syncthreads();
    for (int d = 1; d < 512; d <<= 1) {
        int t = (threadIdx.x >= d) ? s[threadIdx.x - d] : 0;
        __syncthreads();
        s[threadIdx.x] += t;
        __syncthreads();
    }
    if (threadIdx.x < NB) partials[threadIdx.x] = s[threadIdx.x] - v;
}

__global__ void scan3_kernel(const int* __restrict__ cnt, int* __restrict__ offs,
                             const int* __restrict__ partials, int* __restrict__ cursor,
                             float* __restrict__ dinv, int N) {
    int i = blockIdx.x * 256 + threadIdx.x;
    if (i < N) {
        int o = offs[i] + partials[i >> 8];
        offs[i] = o;
        cursor[i] = o;
        dinv[i] = rsqrtf((float)(cnt[i] + 1));   // +1 self loop
    }
}

__global__ void scatter_kernel(const int* __restrict__ row, const int* __restrict__ col,
                               int* __restrict__ cursor, int* __restrict__ sortedRow, int E) {
    int e = blockIdx.x * 256 + threadIdx.x;
    if (e < E) {
        int c = col[e];
        int p = atomicAdd(&cursor[c], 1);
        sortedRow[p] = row[e];
    }
}

// ---------------- weight pre-transpose (fp32 -> bf16 hi/lo, fragment layout [col][k]) ----

__global__ void prep_w(const float* __restrict__ W0, const float* __restrict__ Wmu,
                       const float* __restrict__ Wsig,
                       unsigned short* __restrict__ W0h, unsigned short* __restrict__ W0l,
                       unsigned short* __restrict__ Wmsh, unsigned short* __restrict__ Wmsl) {
    int c = blockIdx.x;
    int k = threadIdx.x;
    if (c < 128) {                               // W0 [256][128] -> [128 cols][256 k]
        float v = W0[k * 128 + c];
        unsigned short h = f2bf(v);
        W0h[c * 256 + k] = h;
        W0l[c * 256 + k] = f2bf(v - bf2f(h));
    } else if (k < 128) {                        // Wmu|Wsig -> [256 cols][128 k]
        int c2 = c - 128;
        float v = (c2 < 128) ? Wmu[k * 128 + c2] : Wsig[k * 128 + (c2 - 128)];
        unsigned short h = f2bf(v);
        Wmsh[c2 * 128 + k] = h;
        Wmsl[c2 * 128 + k] = f2bf(v - bf2f(h));
    }
}

// ---------------- GEMM1: t0_bf16 = x[100k,256] @ W0[256,128] (3-term compensated) --------
// 128 rows/block (4 waves x 32). B staged in LDS per k-half (Bh+Bl = 64KB), XOR-swizzled.

__launch_bounds__(256, 2)
__global__ void gemm1_mfma(const float* __restrict__ x,
                           const unsigned short* __restrict__ Bh,
                           const unsigned short* __restrict__ Bl,
                           char* __restrict__ outc) {
    __shared__ __align__(16) char Bs[65536];    // [hl][128 cols][128 k] bf16, swizzled
    const int tid = threadIdx.x;
    const int wave = tid >> 6, lane = tid & 63;
    const int lrow = lane & 15, lk8 = (lane >> 4) * 8;
    const int r0 = blockIdx.x * 128 + wave * 32;

    f32x4 acc[2][8] = {};
    const float* ap[2];
    #pragma unroll
    for (int m = 0; m < 2; m++) {
        int rm = r0 + m * 16 + lrow;
        if (rm > N_NODES - 1) rm = N_NODES - 1;
        ap[m] = x + (size_t)rm * 256 + lk8;
    }

    for (int kh = 0; kh < 2; kh++) {
        if (kh) __syncthreads();                // protect LDS before restage
        // stage Bh/Bl panels: cols 0..127, k = kh*128 .. +128
        #pragma unroll
        for (int i = 0; i < 8; i++) {
            int c = i * 256 + tid;              // 0..2047
            int colL = c >> 4, k8 = (c & 15) * 8;
            int ldsB = (colL * 256 + k8 * 2) ^ ((colL & 7) << 4);
            *(int4*)(Bs + ldsB) = *(const int4*)(Bh + colL * 256 + kh * 128 + k8);
            *(int4*)(Bs + 32768 + ldsB) = *(const int4*)(Bl + colL * 256 + kh * 128 + k8);
        }
        // prefetch first A slice
        float4 raw[4];
        raw[0] = *(const float4*)(ap[0] + kh * 128);
        raw[1] = *(const float4*)(ap[0] + kh * 128 + 4);
        raw[2] = *(const float4*)(ap[1] + kh * 128);
        raw[3] = *(const float4*)(ap[1] + kh * 128 + 4);
        __syncthreads();

        #pragma unroll
        for (int ki = 0; ki < 4; ki++) {
            float4 nxt[4];
            if (ki < 3) {
                int ko = kh * 128 + (ki + 1) * 32;
                nxt[0] = *(const float4*)(ap[0] + ko);
                nxt[1] = *(const float4*)(ap[0] + ko + 4);
                nxt[2] = *(const float4*)(ap[1] + ko);
                nxt[3] = *(const float4*)(ap[1] + ko + 4);
            }
            bf16x8 ah[2], al[2];
            #pragma unroll
            for (int m = 0; m < 2; m++) {
                float a[8] = {raw[2*m].x, raw[2*m].y, raw[2*m].z, raw[2*m].w,
                              raw[2*m+1].x, raw[2*m+1].y, raw[2*m+1].z, raw[2*m+1].w};
                s16x8 hh, ll;
                #pragma unroll
                for (int j = 0; j < 8; j++) {
                    unsigned short hb = f2bf(a[j]);
                    hh[j] = (short)hb;
                    ll[j] = (short)f2bf(a[j] - bf2f(hb));
                }
                ah[m] = __builtin_bit_cast(bf16x8, hh);
                al[m] = __builtin_bit_cast(bf16x8, ll);
            }
            const int kb = ki * 64 + (lane >> 4) * 16;
            #pragma unroll
            for (int n = 0; n < 8; n++) {
                int colL = n * 16 + lrow;
                int off = (colL * 256 + kb) ^ ((colL & 7) << 4);
                bf16x8 bh = *(const bf16x8*)(Bs + off);
                bf16x8 bl = *(const bf16x8*)(Bs + 32768 + off);
                acc[0][n] = MFMA16(ah[0], bh, acc[0][n]);
                acc[1][n] = MFMA16(ah[1], bh, acc[1][n]);
                acc[0][n] = MFMA16(al[0], bh, acc[0][n]);
                acc[1][n] = MFMA16(al[1], bh, acc[1][n]);
                acc[0][n] = MFMA16(ah[0], bl, acc[0][n]);
                acc[1][n] = MFMA16(ah[1], bl, acc[1][n]);
            }
            #pragma unroll
            for (int j = 0; j < 4; j++) raw[j] = nxt[j];
        }
    }
    // t0 row r lives at outc + r*512 + 256 (128 bf16)
    #pragma unroll
    for (int m = 0; m < 2; m++)
        #pragma unroll
        for (int n = 0; n < 8; n++) {
            int colb = 256 + (n * 16 + lrow) * 2;
            #pragma unroll
            for (int q = 0; q < 4; q++) {
                int row = r0 + m * 16 + (lane >> 4) * 4 + q;
                if (row < N_NODES)
                    *(unsigned short*)(outc + (size_t)row * ROWB + colb) = f2bf(acc[m][n][q]);
            }
        }
}

// ---------------- aggregation over bf16 rows (512B-strided), fp32 accumulate ------------
// 8-wide predicated edge batches: 8 independent row gathers in flight per wave.

template <int EPI>
__launch_bounds__(256)
__global__ void agg_bf16(const char* __restrict__ srcBase, char* __restrict__ dstBase,
                         const int* __restrict__ offs, const int* __restrict__ cnt,
                         const int* __restrict__ sortedRow, const float* __restrict__ dinv,
                         const float* __restrict__ bias) {
    const int n = blockIdx.x * 4 + (threadIdx.x >> 6);
    const int lane = threadIdx.x & 63;
    const float dn = dinv[n];
    const char* srcLane = srcBase + (size_t)lane * 4;
    unsigned int u = *(const unsigned int*)(srcLane + (size_t)n * ROWB);
    const float ws = dn * dn;
    float acc0 = ws * bf_lo(u);
    float acc1 = ws * bf_hi(u);
    const int start = offs[n], num = cnt[n];

    for (int i = 0; i < num; i += 8) {
        int r[8];
        #pragma unroll
        for (int j = 0; j < 8; j++) {
            bool valid = (i + j) < num;
            int idx = start + (valid ? (i + j) : 0);
            int rr = sortedRow[idx];
            r[j] = valid ? rr : n;
        }
        unsigned int ue[8];
        #pragma unroll
        for (int j = 0; j < 8; j++)
            ue[j] = *(const unsigned int*)(srcLane + (size_t)r[j] * ROWB);
        float w[8];
        #pragma unroll
        for (int j = 0; j < 8; j++) {
            float wv = dn * dinv[r[j]];
            w[j] = ((i + j) < num) ? wv : 0.f;
        }
        #pragma unroll
        for (int j = 0; j < 8; j++) {
            acc0 = fmaf(w[j], bf_lo(ue[j]), acc0);
            acc1 = fmaf(w[j], bf_hi(ue[j]), acc1);
        }
    }

    if (EPI) {
        acc0 = fmaxf(acc0 + bias[2 * lane], 0.f);
        acc1 = fmaxf(acc1 + bias[2 * lane + 1], 0.f);
    }
    unsigned int o = (unsigned int)f2bf(acc0) | ((unsigned int)f2bf(acc1) << 16);
    *(unsigned int*)(dstBase + (size_t)n * ROWB + lane * 4) = o;
}

// ---------------- GEMM2: [mu|sigma] = t2_bf16[100k,128] @ [Wmu|Wsig] (2-term) -----------
// 64 rows/block; wave = (rg, ch). A prefetched to regs BEFORE first barrier (its vmcnt
// drain makes the later in-place mu stores race-free). Bh staged (64KB), MFMA pass,
// restage Bl over it, second pass.

__launch_bounds__(256, 2)
__global__ void gemm2_mfma(const unsigned short* __restrict__ Bh,
                           const unsigned short* __restrict__ Bl,
                           const float* __restrict__ bmu, const float* __restrict__ bsig,
                           char* __restrict__ outc) {
    __shared__ __align__(16) char Bs[65536];    // [256 cols][128 k] bf16, swizzled
    const int tid = threadIdx.x;
    const int wave = tid >> 6, lane = tid & 63;
    const int rg = wave >> 1, ch = wave & 1;
    const int lrow = lane & 15, lk8 = (lane >> 4) * 8;
    const int r0 = blockIdx.x * 64 + rg * 32;

    // prefetch ALL A fragments (t2) before any barrier
    bf16x8 a[2][4];
    #pragma unroll
    for (int m = 0; m < 2; m++) {
        int rm = r0 + m * 16 + lrow;
        if (rm > N_NODES - 1) rm = N_NODES - 1;
        const char* apc = outc + (size_t)rm * ROWB + lk8 * 2;
        #pragma unroll
        for (int ki = 0; ki < 4; ki++)
            a[m][ki] = *(const bf16x8*)(apc + ki * 64);
    }

    f32x4 acc[2][8] = {};
    const int kb = (lane >> 4) * 16;

    #pragma unroll
    for (int pass = 0; pass < 2; pass++) {
        if (pass) __syncthreads();              // drain reads before restage
        const unsigned short* W = pass ? Bl : Bh;
        #pragma unroll
        for (int i = 0; i < 16; i++) {
            int c = i * 256 + tid;              // 0..4095
            int colG = c >> 4, k8 = (c & 15) * 8;
            int ldsB = (colG * 256 + k8 * 2) ^ ((colG & 7) << 4);
            *(int4*)(Bs + ldsB) = *(const int4*)(W + colG * 128 + k8);
        }
        __syncthreads();
        #pragma unroll
        for (int ki = 0; ki < 4; ki++)
            #pragma unroll
            for (int n = 0; n < 8; n++) {
                int colG = ch * 128 + n * 16 + lrow;
                int off = (colG * 256 + ki * 64 + kb) ^ ((colG & 7) << 4);
                bf16x8 b = *(const bf16x8*)(Bs + off);
                acc[0][n] = MFMA16(a[0][ki], b, acc[0][n]);
                acc[1][n] = MFMA16(a[1][ki], b, acc[1][n]);
            }
    }

    #pragma unroll
    for (int n = 0; n < 8; n++) {
        int c = n * 16 + lrow;                  // 0..127 within half
        float bv = (ch == 0) ? bmu[c] : bsig[c];
        #pragma unroll
        for (int m = 0; m < 2; m++) {
            f32x4 v = acc[m][n];
            #pragma unroll
            for (int q = 0; q < 4; q++) {
                int row = r0 + m * 16 + (lane >> 4) * 4 + q;
                if (row >= N_NODES) continue;
                float val = v[q] + bv;
                if (ch == 0) {
                    *(float*)(outc + (size_t)row * ROWB + c * 4) = val;
                } else {
                    float sp = fmaxf(val, 0.f) + log1pf(expf(-fabsf(val))) + 1e-7f;
                    *(float*)(outc + HALFB + (size_t)row * ROWB + c * 4) = sp;
                }
            }
        }
    }
}

// ---------------- launch ----------------

extern "C" void kernel_launch(void* const* d_in, const int* in_sizes, int n_in,
                              void* d_out, int out_size, void* d_ws, size_t ws_size,
                              hipStream_t stream) {
    const float* x    = (const float*)d_in[0];
    const int*   ei   = (const int*)d_in[1];
    const int*   row  = ei;
    const int*   col  = ei + N_EDGES;
    const float* W0   = (const float*)d_in[2];
    const float* b0   = (const float*)d_in[3];
    const float* Wmu  = (const float*)d_in[4];
    const float* bmu  = (const float*)d_in[5];
    const float* Wsig = (const float*)d_in[6];
    const float* bsig = (const float*)d_in[7];
    char* outc = (char*)d_out;

    // workspace: weight transposes first (16B aligned), then sort arrays (~8.3MB)
    unsigned short* W0h  = (unsigned short*)d_ws;       // 128*256
    unsigned short* W0l  = W0h + 32768;
    unsigned short* Wmsh = W0l + 32768;                 // 256*128
    unsigned short* Wmsl = Wmsh + 32768;
    int*   cnt       = (int*)(Wmsl + 32768);
    int*   offs      = cnt + N_NODES;
    int*   cursor    = offs + N_NODES;
    float* dinvp     = (float*)(cursor + N_NODES);
    int*   sortedRow = (int*)(dinvp + N_NODES);
    int*   partials  = sortedRow + N_EDGES;             // 512 ints

    const int NB = (N_NODES + 255) / 256;               // 391
    const int EB = (N_EDGES + 255) / 256;               // 6250

    hipMemsetAsync(cnt, 0, N_NODES * sizeof(int), stream);
    count_kernel<<<EB, 256, 0, stream>>>(col, cnt, N_EDGES);
    scan1_kernel<<<NB, 256, 0, stream>>>(cnt, offs, partials, N_NODES);
    scan2_kernel<<<1, 512, 0, stream>>>(partials, NB);
    scan3_kernel<<<NB, 256, 0, stream>>>(cnt, offs, partials, cursor, dinvp, N_NODES);
    scatter_kernel<<<EB, 256, 0, stream>>>(row, col, cursor, sortedRow, N_EDGES);
    prep_w<<<384, 256, 0, stream>>>(W0, Wmu, Wsig, W0h, W0l, Wmsh, Wmsl);

    gemm1_mfma<<<(N_NODES + 127) / 128, 256, 0, stream>>>(x, W0h, W0l, outc);
    // t0 (+256 in mu slots) -> h (sigma slots)
    agg_bf16<1><<<N_NODES / 4, 256, 0, stream>>>(outc + 256, outc + HALFB,
                                                 offs, cnt, sortedRow, dinvp, b0);
    // h -> t2 (+0 in mu slots)
    agg_bf16<0><<<N_NODES / 4, 256, 0, stream>>>(outc + HALFB, outc,
                                                 offs, cnt, sortedRow, dinvp, nullptr);
    gemm2_mfma<<<(N_NODES + 63) / 64, 256, 0, stream>>>(Wmsh, Wmsl, bmu, bsig, outc);
}

// Round 5
// 454.881 us; speedup vs baseline: 1.8126x; 1.0914x over previous
//
#include <hip/hip_runtime.h>
#include <math.h>

#define N_NODES 100000
#define N_EDGES 1600000
#define ROWB    512                 // bytes per row slot in d_out
#define HALFB   51200000ull         // byte offset of second output (sigma half)

typedef float  f32x4  __attribute__((ext_vector_type(4)));
typedef __bf16 bf16x8 __attribute__((ext_vector_type(8)));
typedef short  s16x8  __attribute__((ext_vector_type(8)));

__device__ __forceinline__ unsigned short f2bf(float f) {
    unsigned int u = __builtin_bit_cast(unsigned int, f);
    u += 0x7FFFu + ((u >> 16) & 1u);          // RNE
    return (unsigned short)(u >> 16);
}
__device__ __forceinline__ float bf2f(unsigned short h) {
    unsigned int u = ((unsigned int)h) << 16;
    return __builtin_bit_cast(float, u);
}
__device__ __forceinline__ float bf_lo(unsigned int u) {
    return __builtin_bit_cast(float, u << 16);
}
__device__ __forceinline__ float bf_hi(unsigned int u) {
    return __builtin_bit_cast(float, u & 0xFFFF0000u);
}

#define MFMA16(a, b, c) __builtin_amdgcn_mfma_f32_16x16x32_bf16((a), (b), (c), 0, 0, 0)

// ---------------- degree / counting-sort kernels ----------------

__global__ void count_kernel(const int* __restrict__ col, int* __restrict__ cnt, int E) {
    int e = blockIdx.x * 256 + threadIdx.x;
    if (e < E) atomicAdd(&cnt[col[e]], 1);
}

__global__ void scan1_kernel(const int* __restrict__ cnt, int* __restrict__ offs,
                             int* __restrict__ partials, int N) {
    __shared__ int s[256];
    int i = blockIdx.x * 256 + threadIdx.x;
    int v = (i < N) ? cnt[i] : 0;
    s[threadIdx.x] = v;
    __syncthreads();
    for (int d = 1; d < 256; d <<= 1) {
        int t = (threadIdx.x >= d) ? s[threadIdx.x - d] : 0;
        __syncthreads();
        s[threadIdx.x] += t;
        __syncthreads();
    }
    if (i < N) offs[i] = s[threadIdx.x] - v;
    if (threadIdx.x == 255) partials[blockIdx.x] = s[255];
}

__global__ void scan2_kernel(int* __restrict__ partials, int NB) {
    __shared__ int s[512];
    int v = (threadIdx.x < NB) ? partials[threadIdx.x] : 0;
    s[threadIdx.x] = v;
    __syncthreads();
    for (int d = 1; d < 512; d <<= 1) {
        int t = (threadIdx.x >= d) ? s[threadIdx.x - d] : 0;
        __syncthreads();
        s[threadIdx.x] += t;
        __syncthreads();
    }
    if (threadIdx.x < NB) partials[threadIdx.x] = s[threadIdx.x] - v;
}

__global__ void scan3_kernel(const int* __restrict__ cnt, int* __restrict__ offs,
                             const int* __restrict__ partials, int* __restrict__ cursor,
                             float* __restrict__ dinv, int N) {
    int i = blockIdx.x * 256 + threadIdx.x;
    if (i < N) {
        int o = offs[i] + partials[i >> 8];
        offs[i] = o;
        cursor[i] = o;
        dinv[i] = rsqrtf((float)(cnt[i] + 1));   // +1 self loop
    }
}

__global__ void scatter_kernel(const int* __restrict__ row, const int* __restrict__ col,
                               int* __restrict__ cursor, int* __restrict__ sortedRow, int E) {
    int e = blockIdx.x * 256 + threadIdx.x;
    if (e < E) {
        int c = col[e];
        int p = atomicAdd(&cursor[c], 1);
        sortedRow[p] = row[e];
    }
}

// ---------------- weight pre-transpose (fp32 -> bf16 hi/lo, fragment layout [col][k]) ----

__global__ void prep_w(const float* __restrict__ W0, const float* __restrict__ Wmu,
                       const float* __restrict__ Wsig,
                       unsigned short* __restrict__ W0h, unsigned short* __restrict__ W0l,
                       unsigned short* __restrict__ Wmsh, unsigned short* __restrict__ Wmsl) {
    int c = blockIdx.x;
    int k = threadIdx.x;
    if (c < 128) {                               // W0 [256][128] -> [128 cols][256 k]
        float v = W0[k * 128 + c];
        unsigned short h = f2bf(v);
        W0h[c * 256 + k] = h;
        W0l[c * 256 + k] = f2bf(v - bf2f(h));
    } else if (k < 128) {                        // Wmu|Wsig -> [256 cols][128 k]
        int c2 = c - 128;
        float v = (c2 < 128) ? Wmu[k * 128 + c2] : Wsig[k * 128 + (c2 - 128)];
        unsigned short h = f2bf(v);
        Wmsh[c2 * 128 + k] = h;
        Wmsl[c2 * 128 + k] = f2bf(v - bf2f(h));
    }
}

// ---------------- GEMM1: t0_bf16 = x[100k,256] @ W0[256,128] (3-term compensated) --------
// 512 threads = 8 waves x 16 rows. 32KB LDS panel, 4 passes: (kh0,Bh),(kh0,Bl),(kh1,Bh),(kh1,Bl).

__launch_bounds__(512, 4)
__global__ void gemm1_mfma(const float* __restrict__ x,
                           const unsigned short* __restrict__ Bh,
                           const unsigned short* __restrict__ Bl,
                           char* __restrict__ outc) {
    __shared__ __align__(16) char Bs[32768];    // [128 cols][128 k] bf16, swizzled
    const int tid = threadIdx.x;
    const int wave = tid >> 6, lane = tid & 63;
    const int lrow = lane & 15;
    const int lk8 = (lane >> 4) * 8;
    const int kb = (lane >> 4) * 16;
    const int r0 = blockIdx.x * 128 + wave * 16;
    int rm = r0 + lrow; if (rm > N_NODES - 1) rm = N_NODES - 1;
    const float* ap = x + (size_t)rm * 256 + lk8;

    f32x4 acc[8] = {};
    for (int kh = 0; kh < 2; kh++) {
        // load + split A for this k-half (persists across both hl passes)
        float4 ra[4], rb[4];
        #pragma unroll
        for (int ki = 0; ki < 4; ki++) {
            ra[ki] = *(const float4*)(ap + kh * 128 + ki * 32);
            rb[ki] = *(const float4*)(ap + kh * 128 + ki * 32 + 4);
        }
        bf16x8 ah[4], al[4];
        #pragma unroll
        for (int ki = 0; ki < 4; ki++) {
            float a[8] = {ra[ki].x, ra[ki].y, ra[ki].z, ra[ki].w,
                          rb[ki].x, rb[ki].y, rb[ki].z, rb[ki].w};
            s16x8 hh, ll;
            #pragma unroll
            for (int j = 0; j < 8; j++) {
                unsigned short hb = f2bf(a[j]);
                hh[j] = (short)hb;
                ll[j] = (short)f2bf(a[j] - bf2f(hb));
            }
            ah[ki] = __builtin_bit_cast(bf16x8, hh);
            al[ki] = __builtin_bit_cast(bf16x8, ll);
        }
        #pragma unroll
        for (int hl = 0; hl < 2; hl++) {
            __syncthreads();                    // previous panel's reads done
            const unsigned short* W = hl ? Bl : Bh;
            #pragma unroll
            for (int i = 0; i < 4; i++) {
                int c = i * 512 + tid;          // 0..2047
                int colL = c >> 4, k8 = (c & 15) * 8;
                int ldsB = (colL * 256 + k8 * 2) ^ ((colL & 7) << 4);
                *(int4*)(Bs + ldsB) = *(const int4*)(W + colL * 256 + kh * 128 + k8);
            }
            __syncthreads();
            #pragma unroll
            for (int ki = 0; ki < 4; ki++)
                #pragma unroll
                for (int n = 0; n < 8; n++) {
                    int colL = n * 16 + lrow;
                    int off = (colL * 256 + ki * 64 + kb) ^ ((colL & 7) << 4);
                    bf16x8 b = *(const bf16x8*)(Bs + off);
                    acc[n] = MFMA16(ah[ki], b, acc[n]);
                    if (hl == 0) acc[n] = MFMA16(al[ki], b, acc[n]);
                }
        }
    }
    // t0 row r lives at outc + r*512 + 256 (128 bf16)
    #pragma unroll
    for (int n = 0; n < 8; n++) {
        int colb = 256 + (n * 16 + lrow) * 2;
        #pragma unroll
        for (int q = 0; q < 4; q++) {
            int row = r0 + (lane >> 4) * 4 + q;
            if (row < N_NODES)
                *(unsigned short*)(outc + (size_t)row * ROWB + colb) = f2bf(acc[n][q]);
        }
    }
}

// ---------------- aggregation over bf16 rows (512B-strided), fp32 accumulate ------------
// 8-wide predicated edge batches: 8 independent row gathers in flight per wave.

template <int EPI>
__launch_bounds__(256)
__global__ void agg_bf16(const char* __restrict__ srcBase, char* __restrict__ dstBase,
                         const int* __restrict__ offs, const int* __restrict__ cnt,
                         const int* __restrict__ sortedRow, const float* __restrict__ dinv,
                         const float* __restrict__ bias) {
    const int n = blockIdx.x * 4 + (threadIdx.x >> 6);
    const int lane = threadIdx.x & 63;
    const float dn = dinv[n];
    const char* srcLane = srcBase + (size_t)lane * 4;
    unsigned int u = *(const unsigned int*)(srcLane + (size_t)n * ROWB);
    const float ws = dn * dn;
    float acc0 = ws * bf_lo(u);
    float acc1 = ws * bf_hi(u);
    const int start = offs[n], num = cnt[n];

    for (int i = 0; i < num; i += 8) {
        int r[8];
        #pragma unroll
        for (int j = 0; j < 8; j++) {
            bool valid = (i + j) < num;
            int idx = start + (valid ? (i + j) : 0);
            int rr = sortedRow[idx];
            r[j] = valid ? rr : n;
        }
        unsigned int ue[8];
        #pragma unroll
        for (int j = 0; j < 8; j++)
            ue[j] = *(const unsigned int*)(srcLane + (size_t)r[j] * ROWB);
        float w[8];
        #pragma unroll
        for (int j = 0; j < 8; j++) {
            float wv = dn * dinv[r[j]];
            w[j] = ((i + j) < num) ? wv : 0.f;
        }
        #pragma unroll
        for (int j = 0; j < 8; j++) {
            acc0 = fmaf(w[j], bf_lo(ue[j]), acc0);
            acc1 = fmaf(w[j], bf_hi(ue[j]), acc1);
        }
    }

    if (EPI) {
        acc0 = fmaxf(acc0 + bias[2 * lane], 0.f);
        acc1 = fmaxf(acc1 + bias[2 * lane + 1], 0.f);
    }
    unsigned int o = (unsigned int)f2bf(acc0) | ((unsigned int)f2bf(acc1) << 16);
    *(unsigned int*)(dstBase + (size_t)n * ROWB + lane * 4) = o;
}

// ---------------- GEMM2: [mu|sigma] = t2_bf16[100k,128] @ [Wmu|Wsig] (2-term) -----------
// 512 threads = 8 waves x 16 rows. A held in regs (prefetched before first barrier; the
// barrier's vmcnt drain makes the in-place mu stores safe). 32KB panel, 4 passes:
// (mu,h),(mu,l) -> mu epilogue -> (sig,h),(sig,l) -> sigma epilogue.

__launch_bounds__(512, 4)
__global__ void gemm2_mfma(const unsigned short* __restrict__ Bh,
                           const unsigned short* __restrict__ Bl,
                           const float* __restrict__ bmu, const float* __restrict__ bsig,
                           char* __restrict__ outc) {
    __shared__ __align__(16) char Bs[32768];    // [128 cols][128 k] bf16, swizzled
    const int tid = threadIdx.x;
    const int wave = tid >> 6, lane = tid & 63;
    const int lrow = lane & 15;
    const int lk8 = (lane >> 4) * 8;
    const int kb = (lane >> 4) * 16;
    const int r0 = blockIdx.x * 128 + wave * 16;
    int rm = r0 + lrow; if (rm > N_NODES - 1) rm = N_NODES - 1;

    // prefetch ALL A fragments (t2) before any barrier
    const char* apc = outc + (size_t)rm * ROWB + lk8 * 2;
    bf16x8 a[4];
    #pragma unroll
    for (int ki = 0; ki < 4; ki++)
        a[ki] = *(const bf16x8*)(apc + ki * 64);

    #pragma unroll
    for (int half = 0; half < 2; half++) {
        f32x4 acc[8] = {};
        #pragma unroll
        for (int hl = 0; hl < 2; hl++) {
            __syncthreads();                    // previous panel's reads done
            const unsigned short* W = (hl ? Bl : Bh) + half * 16384;
            #pragma unroll
            for (int i = 0; i < 4; i++) {
                int c = i * 512 + tid;          // 0..2047
                int colL = c >> 4, k8 = (c & 15) * 8;
                int ldsB = (colL * 256 + k8 * 2) ^ ((colL & 7) << 4);
                *(int4*)(Bs + ldsB) = *(const int4*)(W + colL * 128 + k8);
            }
            __syncthreads();
            #pragma unroll
            for (int ki = 0; ki < 4; ki++)
                #pragma unroll
                for (int n = 0; n < 8; n++) {
                    int colL = n * 16 + lrow;
                    int off = (colL * 256 + ki * 64 + kb) ^ ((colL & 7) << 4);
                    bf16x8 b = *(const bf16x8*)(Bs + off);
                    acc[n] = MFMA16(a[ki], b, acc[n]);
                }
        }
        #pragma unroll
        for (int n = 0; n < 8; n++) {
            int c = n * 16 + lrow;              // 0..127 within half
            float bv = half ? bsig[c] : bmu[c];
            #pragma unroll
            for (int q = 0; q < 4; q++) {
                int row = r0 + (lane >> 4) * 4 + q;
                if (row >= N_NODES) continue;
                float val = acc[n][q] + bv;
                if (half == 0) {
                    *(float*)(outc + (size_t)row * ROWB + c * 4) = val;
                } else {
                    float sp = fmaxf(val, 0.f) + log1pf(expf(-fabsf(val))) + 1e-7f;
                    *(float*)(outc + HALFB + (size_t)row * ROWB + c * 4) = sp;
                }
            }
        }
    }
}

// ---------------- launch ----------------

extern "C" void kernel_launch(void* const* d_in, const int* in_sizes, int n_in,
                              void* d_out, int out_size, void* d_ws, size_t ws_size,
                              hipStream_t stream) {
    const float* x    = (const float*)d_in[0];
    const int*   ei   = (const int*)d_in[1];
    const int*   row  = ei;
    const int*   col  = ei + N_EDGES;
    const float* W0   = (const float*)d_in[2];
    const float* b0   = (const float*)d_in[3];
    const float* Wmu  = (const float*)d_in[4];
    const float* bmu  = (const float*)d_in[5];
    const float* Wsig = (const float*)d_in[6];
    const float* bsig = (const float*)d_in[7];
    char* outc = (char*)d_out;

    // workspace: weight transposes first (16B aligned), then sort arrays (~8.3MB)
    unsigned short* W0h  = (unsigned short*)d_ws;       // 128*256
    unsigned short* W0l  = W0h + 32768;
    unsigned short* Wmsh = W0l + 32768;                 // 256*128
    unsigned short* Wmsl = Wmsh + 32768;
    int*   cnt       = (int*)(Wmsl + 32768);
    int*   offs      = cnt + N_NODES;
    int*   cursor    = offs + N_NODES;
    float* dinvp     = (float*)(cursor + N_NODES);
    int*   sortedRow = (int*)(dinvp + N_NODES);
    int*   partials  = sortedRow + N_EDGES;             // 512 ints

    const int NB = (N_NODES + 255) / 256;               // 391
    const int EB = (N_EDGES + 255) / 256;               // 6250

    hipMemsetAsync(cnt, 0, N_NODES * sizeof(int), stream);
    count_kernel<<<EB, 256, 0, stream>>>(col, cnt, N_EDGES);
    scan1_kernel<<<NB, 256, 0, stream>>>(cnt, offs, partials, N_NODES);
    scan2_kernel<<<1, 512, 0, stream>>>(partials, NB);
    scan3_kernel<<<NB, 256, 0, stream>>>(cnt, offs, partials, cursor, dinvp, N_NODES);
    scatter_kernel<<<EB, 256, 0, stream>>>(row, col, cursor, sortedRow, N_EDGES);
    prep_w<<<384, 256, 0, stream>>>(W0, Wmu, Wsig, W0h, W0l, Wmsh, Wmsl);

    gemm1_mfma<<<(N_NODES + 127) / 128, 512, 0, stream>>>(x, W0h, W0l, outc);
    // t0 (+256 in mu slots) -> h (sigma slots)
    agg_bf16<1><<<N_NODES / 4, 256, 0, stream>>>(outc + 256, outc + HALFB,
                                                 offs, cnt, sortedRow, dinvp, b0);
    // h -> t2 (+0 in mu slots)
    agg_bf16<0><<<N_NODES / 4, 256, 0, stream>>>(outc + HALFB, outc,
                                                 offs, cnt, sortedRow, dinvp, nullptr);
    gemm2_mfma<<<(N_NODES + 127) / 128, 512, 0, stream>>>(Wmsh, Wmsl, bmu, bsig, outc);
}

// Round 6
// 391.435 us; speedup vs baseline: 2.1063x; 1.1621x over previous
//
#include <hip/hip_runtime.h>
#include <math.h>

#define N_NODES 100000
#define N_EDGES 1600000
#define ROWB    512                 // bytes per row slot in d_out
#define HALFB   51200000ull         // byte offset of second output (sigma half)
#define NBKT    196                 // sort buckets (512 dst nodes each)
#define BSH     9
#define BCAP    10240               // entries per bucket (mean 8192, >20 sigma margin)

typedef float  f32x4  __attribute__((ext_vector_type(4)));
typedef __bf16 bf16x8 __attribute__((ext_vector_type(8)));
typedef short  s16x8  __attribute__((ext_vector_type(8)));

__device__ __forceinline__ unsigned short f2bf(float f) {
    unsigned int u = __builtin_bit_cast(unsigned int, f);
    u += 0x7FFFu + ((u >> 16) & 1u);          // RNE
    return (unsigned short)(u >> 16);
}
__device__ __forceinline__ float bf2f(unsigned short h) {
    unsigned int u = ((unsigned int)h) << 16;
    return __builtin_bit_cast(float, u);
}
__device__ __forceinline__ float bf_lo(unsigned int u) {
    return __builtin_bit_cast(float, u << 16);
}
__device__ __forceinline__ float bf_hi(unsigned int u) {
    return __builtin_bit_cast(float, u & 0xFFFF0000u);
}

#define MFMA16(a, b, c) __builtin_amdgcn_mfma_f32_16x16x32_bf16((a), (b), (c), 0, 0, 0)

// ---------------- sort pass B: bucket-binning + degree count ----------------
// 391 blocks x 4096 edges. LDS histogram -> one global atomic per (block,bucket) ->
// dense per-bucket append of packed (col,row). Degree count folded in.

__launch_bounds__(256)
__global__ void bin_kernel(const int* __restrict__ row, const int* __restrict__ col,
                           int* __restrict__ cnt, int* __restrict__ gcur,
                           unsigned long long* __restrict__ entries) {
    __shared__ int hist[NBKT], base[NBKT], cur[NBKT];
    const int tid = threadIdx.x;
    for (int i = tid; i < NBKT; i += 256) { hist[i] = 0; cur[i] = 0; }
    __syncthreads();
    const int e0 = blockIdx.x * 4096;
    int cols[16];
    #pragma unroll
    for (int it = 0; it < 16; it++) {
        int e = e0 + it * 256 + tid;
        int c = (e < N_EDGES) ? col[e] : -1;
        cols[it] = c;
        if (c >= 0) {
            atomicAdd(&hist[c >> BSH], 1);
            atomicAdd(&cnt[c], 1);
        }
    }
    __syncthreads();
    for (int i = tid; i < NBKT; i += 256)
        base[i] = atomicAdd(&gcur[i], hist[i]);
    __syncthreads();
    #pragma unroll
    for (int it = 0; it < 16; it++) {
        int e = e0 + it * 256 + tid;
        int c = cols[it];
        if (c >= 0) {
            int b = c >> BSH;
            int r = atomicAdd(&cur[b], 1);
            unsigned long long pk =
                ((unsigned long long)(unsigned)c << 32) | (unsigned)row[e];
            entries[(size_t)b * BCAP + base[b] + r] = pk;
        }
    }
}

// ---------------- scans (exclusive prefix over per-node counts) ----------------

__global__ void scan1_kernel(const int* __restrict__ cnt, int* __restrict__ offs,
                             int* __restrict__ partials, int N) {
    __shared__ int s[256];
    int i = blockIdx.x * 256 + threadIdx.x;
    int v = (i < N) ? cnt[i] : 0;
    s[threadIdx.x] = v;
    __syncthreads();
    for (int d = 1; d < 256; d <<= 1) {
        int t = (threadIdx.x >= d) ? s[threadIdx.x - d] : 0;
        __syncthreads();
        s[threadIdx.x] += t;
        __syncthreads();
    }
    if (i < N) offs[i] = s[threadIdx.x] - v;
    if (threadIdx.x == 255) partials[blockIdx.x] = s[255];
}

__global__ void scan2_kernel(int* __restrict__ partials, int NB) {
    __shared__ int s[512];
    int v = (threadIdx.x < NB) ? partials[threadIdx.x] : 0;
    s[threadIdx.x] = v;
    __syncthreads();
    for (int d = 1; d < 512; d <<= 1) {
        int t = (threadIdx.x >= d) ? s[threadIdx.x - d] : 0;
        __syncthreads();
        s[threadIdx.x] += t;
        __syncthreads();
    }
    if (threadIdx.x < NB) partials[threadIdx.x] = s[threadIdx.x] - v;
}

__global__ void scan3_kernel(const int* __restrict__ cnt, int* __restrict__ offs,
                             const int* __restrict__ partials, int* __restrict__ cursor,
                             float* __restrict__ dinv, int N) {
    int i = blockIdx.x * 256 + threadIdx.x;
    if (i < N) {
        int o = offs[i] + partials[i >> 8];
        offs[i] = o;
        cursor[i] = o;
        dinv[i] = rsqrtf((float)(cnt[i] + 1));   // +1 self loop
    }
}

// ---------------- sort pass C: per-bucket CSR scatter (L2-resident windows) -------------

__launch_bounds__(256)
__global__ void csr_kernel(const unsigned long long* __restrict__ entries,
                           const int* __restrict__ gcnt,
                           int* __restrict__ cursor, int* __restrict__ sortedRow) {
    const int b = blockIdx.x;
    const int nb = gcnt[b];
    const unsigned long long* ep = entries + (size_t)b * BCAP;
    for (int i = threadIdx.x; i < nb; i += 256) {
        unsigned long long pk = ep[i];
        int c = (int)(pk >> 32);
        int r = (int)(pk & 0xFFFFFFFFu);
        int p = atomicAdd(&cursor[c], 1);
        sortedRow[p] = r;
    }
}

// ---------------- weight pre-transpose (fp32 -> bf16 hi/lo, fragment layout [col][k]) ----

__global__ void prep_w(const float* __restrict__ W0, const float* __restrict__ Wmu,
                       const float* __restrict__ Wsig,
                       unsigned short* __restrict__ W0h, unsigned short* __restrict__ W0l,
                       unsigned short* __restrict__ Wmsh, unsigned short* __restrict__ Wmsl) {
    int c = blockIdx.x;
    int k = threadIdx.x;
    if (c < 128) {                               // W0 [256][128] -> [128 cols][256 k]
        float v = W0[k * 128 + c];
        unsigned short h = f2bf(v);
        W0h[c * 256 + k] = h;
        W0l[c * 256 + k] = f2bf(v - bf2f(h));
    } else if (k < 128) {                        // Wmu|Wsig -> [256 cols][128 k]
        int c2 = c - 128;
        float v = (c2 < 128) ? Wmu[k * 128 + c2] : Wsig[k * 128 + (c2 - 128)];
        unsigned short h = f2bf(v);
        Wmsh[c2 * 128 + k] = h;
        Wmsl[c2 * 128 + k] = f2bf(v - bf2f(h));
    }
}

// ---------------- GEMM1: t0_bf16 = x[100k,256] @ W0[256,128] (3-term compensated) --------
// 512 threads = 8 waves x 16 rows. 32KB LDS panel, 4 passes: (kh0,Bh),(kh0,Bl),(kh1,Bh),(kh1,Bl).

__launch_bounds__(512, 4)
__global__ void gemm1_mfma(const float* __restrict__ x,
                           const unsigned short* __restrict__ Bh,
                           const unsigned short* __restrict__ Bl,
                           char* __restrict__ outc) {
    __shared__ __align__(16) char Bs[32768];    // [128 cols][128 k] bf16, swizzled
    const int tid = threadIdx.x;
    const int wave = tid >> 6, lane = tid & 63;
    const int lrow = lane & 15;
    const int lk8 = (lane >> 4) * 8;
    const int kb = (lane >> 4) * 16;
    const int r0 = blockIdx.x * 128 + wave * 16;
    int rm = r0 + lrow; if (rm > N_NODES - 1) rm = N_NODES - 1;
    const float* ap = x + (size_t)rm * 256 + lk8;

    f32x4 acc[8] = {};
    for (int kh = 0; kh < 2; kh++) {
        // load + split A for this k-half (persists across both hl passes)
        float4 ra[4], rb[4];
        #pragma unroll
        for (int ki = 0; ki < 4; ki++) {
            ra[ki] = *(const float4*)(ap + kh * 128 + ki * 32);
            rb[ki] = *(const float4*)(ap + kh * 128 + ki * 32 + 4);
        }
        bf16x8 ah[4], al[4];
        #pragma unroll
        for (int ki = 0; ki < 4; ki++) {
            float a[8] = {ra[ki].x, ra[ki].y, ra[ki].z, ra[ki].w,
                          rb[ki].x, rb[ki].y, rb[ki].z, rb[ki].w};
            s16x8 hh, ll;
            #pragma unroll
            for (int j = 0; j < 8; j++) {
                unsigned short hb = f2bf(a[j]);
                hh[j] = (short)hb;
                ll[j] = (short)f2bf(a[j] - bf2f(hb));
            }
            ah[ki] = __builtin_bit_cast(bf16x8, hh);
            al[ki] = __builtin_bit_cast(bf16x8, ll);
        }
        #pragma unroll
        for (int hl = 0; hl < 2; hl++) {
            __syncthreads();                    // previous panel's reads done
            const unsigned short* W = hl ? Bl : Bh;
            #pragma unroll
            for (int i = 0; i < 4; i++) {
                int c = i * 512 + tid;          // 0..2047
                int colL = c >> 4, k8 = (c & 15) * 8;
                int ldsB = (colL * 256 + k8 * 2) ^ ((colL & 7) << 4);
                *(int4*)(Bs + ldsB) = *(const int4*)(W + colL * 256 + kh * 128 + k8);
            }
            __syncthreads();
            #pragma unroll
            for (int ki = 0; ki < 4; ki++)
                #pragma unroll
                for (int n = 0; n < 8; n++) {
                    int colL = n * 16 + lrow;
                    int off = (colL * 256 + ki * 64 + kb) ^ ((colL & 7) << 4);
                    bf16x8 b = *(const bf16x8*)(Bs + off);
                    acc[n] = MFMA16(ah[ki], b, acc[n]);
                    if (hl == 0) acc[n] = MFMA16(al[ki], b, acc[n]);
                }
        }
    }
    // t0 row r lives at outc + r*512 + 256 (128 bf16)
    #pragma unroll
    for (int n = 0; n < 8; n++) {
        int colb = 256 + (n * 16 + lrow) * 2;
        #pragma unroll
        for (int q = 0; q < 4; q++) {
            int row = r0 + (lane >> 4) * 4 + q;
            if (row < N_NODES)
                *(unsigned short*)(outc + (size_t)row * ROWB + colb) = f2bf(acc[n][q]);
        }
    }
}

// ---------------- aggregation over bf16 rows (512B-strided), fp32 accumulate ------------
// 8-wide predicated edge batches: 8 independent row gathers in flight per wave.

template <int EPI>
__launch_bounds__(256)
__global__ void agg_bf16(const char* __restrict__ srcBase, char* __restrict__ dstBase,
                         const int* __restrict__ offs, const int* __restrict__ cnt,
                         const int* __restrict__ sortedRow, const float* __restrict__ dinv,
                         const float* __restrict__ bias) {
    const int n = blockIdx.x * 4 + (threadIdx.x >> 6);
    const int lane = threadIdx.x & 63;
    const float dn = dinv[n];
    const char* srcLane = srcBase + (size_t)lane * 4;
    unsigned int u = *(const unsigned int*)(srcLane + (size_t)n * ROWB);
    const float ws = dn * dn;
    float acc0 = ws * bf_lo(u);
    float acc1 = ws * bf_hi(u);
    const int start = offs[n], num = cnt[n];

    for (int i = 0; i < num; i += 8) {
        int r[8];
        #pragma unroll
        for (int j = 0; j < 8; j++) {
            bool valid = (i + j) < num;
            int idx = start + (valid ? (i + j) : 0);
            int rr = sortedRow[idx];
            r[j] = valid ? rr : n;
        }
        unsigned int ue[8];
        #pragma unroll
        for (int j = 0; j < 8; j++)
            ue[j] = *(const unsigned int*)(srcLane + (size_t)r[j] * ROWB);
        float w[8];
        #pragma unroll
        for (int j = 0; j < 8; j++) {
            float wv = dn * dinv[r[j]];
            w[j] = ((i + j) < num) ? wv : 0.f;
        }
        #pragma unroll
        for (int j = 0; j < 8; j++) {
            acc0 = fmaf(w[j], bf_lo(ue[j]), acc0);
            acc1 = fmaf(w[j], bf_hi(ue[j]), acc1);
        }
    }

    if (EPI) {
        acc0 = fmaxf(acc0 + bias[2 * lane], 0.f);
        acc1 = fmaxf(acc1 + bias[2 * lane + 1], 0.f);
    }
    unsigned int o = (unsigned int)f2bf(acc0) | ((unsigned int)f2bf(acc1) << 16);
    *(unsigned int*)(dstBase + (size_t)n * ROWB + lane * 4) = o;
}

// ---------------- GEMM2: [mu|sigma] = t2_bf16[100k,128] @ [Wmu|Wsig] (2-term) -----------
// 512 threads = 8 waves x 16 rows. A held in regs (prefetched before first barrier; the
// barrier's vmcnt drain makes the in-place mu stores safe). 32KB panel, 4 passes.

__launch_bounds__(512, 4)
__global__ void gemm2_mfma(const unsigned short* __restrict__ Bh,
                           const unsigned short* __restrict__ Bl,
                           const float* __restrict__ bmu, const float* __restrict__ bsig,
                           char* __restrict__ outc) {
    __shared__ __align__(16) char Bs[32768];    // [128 cols][128 k] bf16, swizzled
    const int tid = threadIdx.x;
    const int wave = tid >> 6, lane = tid & 63;
    const int lrow = lane & 15;
    const int lk8 = (lane >> 4) * 8;
    const int kb = (lane >> 4) * 16;
    const int r0 = blockIdx.x * 128 + wave * 16;
    int rm = r0 + lrow; if (rm > N_NODES - 1) rm = N_NODES - 1;

    // prefetch ALL A fragments (t2) before any barrier
    const char* apc = outc + (size_t)rm * ROWB + lk8 * 2;
    bf16x8 a[4];
    #pragma unroll
    for (int ki = 0; ki < 4; ki++)
        a[ki] = *(const bf16x8*)(apc + ki * 64);

    #pragma unroll
    for (int half = 0; half < 2; half++) {
        f32x4 acc[8] = {};
        #pragma unroll
        for (int hl = 0; hl < 2; hl++) {
            __syncthreads();                    // previous panel's reads done
            const unsigned short* W = (hl ? Bl : Bh) + half * 16384;
            #pragma unroll
            for (int i = 0; i < 4; i++) {
                int c = i * 512 + tid;          // 0..2047
                int colL = c >> 4, k8 = (c & 15) * 8;
                int ldsB = (colL * 256 + k8 * 2) ^ ((colL & 7) << 4);
                *(int4*)(Bs + ldsB) = *(const int4*)(W + colL * 128 + k8);
            }
            __syncthreads();
            #pragma unroll
            for (int ki = 0; ki < 4; ki++)
                #pragma unroll
                for (int n = 0; n < 8; n++) {
                    int colL = n * 16 + lrow;
                    int off = (colL * 256 + ki * 64 + kb) ^ ((colL & 7) << 4);
                    bf16x8 b = *(const bf16x8*)(Bs + off);
                    acc[n] = MFMA16(a[ki], b, acc[n]);
                }
        }
        #pragma unroll
        for (int n = 0; n < 8; n++) {
            int c = n * 16 + lrow;              // 0..127 within half
            float bv = half ? bsig[c] : bmu[c];
            #pragma unroll
            for (int q = 0; q < 4; q++) {
                int row = r0 + (lane >> 4) * 4 + q;
                if (row >= N_NODES) continue;
                float val = acc[n][q] + bv;
                if (half == 0) {
                    *(float*)(outc + (size_t)row * ROWB + c * 4) = val;
                } else {
                    float sp = fmaxf(val, 0.f) + log1pf(expf(-fabsf(val))) + 1e-7f;
                    *(float*)(outc + HALFB + (size_t)row * ROWB + c * 4) = sp;
                }
            }
        }
    }
}

// ---------------- launch ----------------

extern "C" void kernel_launch(void* const* d_in, const int* in_sizes, int n_in,
                              void* d_out, int out_size, void* d_ws, size_t ws_size,
                              hipStream_t stream) {
    const float* x    = (const float*)d_in[0];
    const int*   ei   = (const int*)d_in[1];
    const int*   row  = ei;
    const int*   col  = ei + N_EDGES;
    const float* W0   = (const float*)d_in[2];
    const float* b0   = (const float*)d_in[3];
    const float* Wmu  = (const float*)d_in[4];
    const float* bmu  = (const float*)d_in[5];
    const float* Wsig = (const float*)d_in[6];
    const float* bsig = (const float*)d_in[7];
    char* outc = (char*)d_out;

    // workspace: weight transposes first (16B aligned), then sort arrays (~8.3MB)
    unsigned short* W0h  = (unsigned short*)d_ws;       // 128*256
    unsigned short* W0l  = W0h + 32768;
    unsigned short* Wmsh = W0l + 32768;                 // 256*128
    unsigned short* Wmsl = Wmsh + 32768;
    int*   cnt       = (int*)(Wmsl + 32768);
    int*   gcur      = cnt + N_NODES;                   // NBKT ints (memset with cnt)
    int*   offs      = gcur + NBKT;
    int*   cursor    = offs + N_NODES;
    float* dinvp     = (float*)(cursor + N_NODES);
    int*   sortedRow = (int*)(dinvp + N_NODES);
    int*   partials  = sortedRow + N_EDGES;             // 512 ints

    // bucket entry scratch lives in d_out's sigma half (free until agg1 writes h)
    unsigned long long* entries = (unsigned long long*)(outc + HALFB);

    const int NB = (N_NODES + 255) / 256;               // 391

    hipMemsetAsync(cnt, 0, (N_NODES + NBKT) * sizeof(int), stream);
    prep_w<<<384, 256, 0, stream>>>(W0, Wmu, Wsig, W0h, W0l, Wmsh, Wmsl);
    bin_kernel<<<(N_EDGES + 4095) / 4096, 256, 0, stream>>>(row, col, cnt, gcur, entries);
    scan1_kernel<<<NB, 256, 0, stream>>>(cnt, offs, partials, N_NODES);
    scan2_kernel<<<1, 512, 0, stream>>>(partials, NB);
    scan3_kernel<<<NB, 256, 0, stream>>>(cnt, offs, partials, cursor, dinvp, N_NODES);
    csr_kernel<<<NBKT, 256, 0, stream>>>(entries, gcur, cursor, sortedRow);

    gemm1_mfma<<<(N_NODES + 127) / 128, 512, 0, stream>>>(x, W0h, W0l, outc);
    // t0 (+256 in mu slots) -> h (sigma slots)
    agg_bf16<1><<<N_NODES / 4, 256, 0, stream>>>(outc + 256, outc + HALFB,
                                                 offs, cnt, sortedRow, dinvp, b0);
    // h -> t2 (+0 in mu slots)
    agg_bf16<0><<<N_NODES / 4, 256, 0, stream>>>(outc + HALFB, outc,
                                                 offs, cnt, sortedRow, dinvp, nullptr);
    gemm2_mfma<<<(N_NODES + 127) / 128, 512, 0, stream>>>(Wmsh, Wmsl, bmu, bsig, outc);
}

// Round 7
// 371.082 us; speedup vs baseline: 2.2219x; 1.0548x over previous
//
#include <hip/hip_runtime.h>
#include <math.h>

#define N_NODES 100000
#define N_EDGES 1600000
#define ROWB    512                 // bytes per row slot in d_out
#define HALFB   51200000ull         // byte offset of second output (sigma half)
#define NBKT    196                 // sort buckets (512 dst nodes each)
#define BSH     9
#define BCAP    10240               // entries per bucket (mean 8192, >20 sigma margin)

typedef float  f32x4  __attribute__((ext_vector_type(4)));
typedef __bf16 bf16x8 __attribute__((ext_vector_type(8)));
typedef short  s16x8  __attribute__((ext_vector_type(8)));

__device__ __forceinline__ unsigned short f2bf(float f) {
    unsigned int u = __builtin_bit_cast(unsigned int, f);
    u += 0x7FFFu + ((u >> 16) & 1u);          // RNE
    return (unsigned short)(u >> 16);
}
__device__ __forceinline__ float bf2f(unsigned short h) {
    unsigned int u = ((unsigned int)h) << 16;
    return __builtin_bit_cast(float, u);
}
__device__ __forceinline__ float bf_lo(unsigned int u) {
    return __builtin_bit_cast(float, u << 16);
}
__device__ __forceinline__ float bf_hi(unsigned int u) {
    return __builtin_bit_cast(float, u & 0xFFFF0000u);
}
__device__ __forceinline__ void splitx(const float4& a, const float4& b,
                                       bf16x8& hi, bf16x8& lo) {
    float v[8] = {a.x, a.y, a.z, a.w, b.x, b.y, b.z, b.w};
    s16x8 hh, ll;
    #pragma unroll
    for (int j = 0; j < 8; j++) {
        unsigned short hb = f2bf(v[j]);
        hh[j] = (short)hb;
        ll[j] = (short)f2bf(v[j] - bf2f(hb));
    }
    hi = __builtin_bit_cast(bf16x8, hh);
    lo = __builtin_bit_cast(bf16x8, ll);
}

#define MFMA16(a, b, c) __builtin_amdgcn_mfma_f32_16x16x32_bf16((a), (b), (c), 0, 0, 0)

// ---------------- sort pass B: bucket-binning + degree count ----------------

__launch_bounds__(256)
__global__ void bin_kernel(const int* __restrict__ row, const int* __restrict__ col,
                           int* __restrict__ cnt, int* __restrict__ gcur,
                           unsigned long long* __restrict__ entries) {
    __shared__ int hist[NBKT], base[NBKT], cur[NBKT];
    const int tid = threadIdx.x;
    for (int i = tid; i < NBKT; i += 256) { hist[i] = 0; cur[i] = 0; }
    __syncthreads();
    const int e0 = blockIdx.x * 4096;
    int cols[16];
    #pragma unroll
    for (int it = 0; it < 16; it++) {
        int e = e0 + it * 256 + tid;
        int c = (e < N_EDGES) ? col[e] : -1;
        cols[it] = c;
        if (c >= 0) {
            atomicAdd(&hist[c >> BSH], 1);
            atomicAdd(&cnt[c], 1);
        }
    }
    __syncthreads();
    for (int i = tid; i < NBKT; i += 256)
        base[i] = atomicAdd(&gcur[i], hist[i]);
    __syncthreads();
    #pragma unroll
    for (int it = 0; it < 16; it++) {
        int e = e0 + it * 256 + tid;
        int c = cols[it];
        if (c >= 0) {
            int b = c >> BSH;
            int r = atomicAdd(&cur[b], 1);
            unsigned long long pk =
                ((unsigned long long)(unsigned)c << 32) | (unsigned)row[e];
            entries[(size_t)b * BCAP + base[b] + r] = pk;
        }
    }
}

// ---------------- scans ----------------

__global__ void scan1_kernel(const int* __restrict__ cnt, int* __restrict__ offs,
                             int* __restrict__ partials, int N) {
    __shared__ int s[256];
    int i = blockIdx.x * 256 + threadIdx.x;
    int v = (i < N) ? cnt[i] : 0;
    s[threadIdx.x] = v;
    __syncthreads();
    for (int d = 1; d < 256; d <<= 1) {
        int t = (threadIdx.x >= d) ? s[threadIdx.x - d] : 0;
        __syncthreads();
        s[threadIdx.x] += t;
        __syncthreads();
    }
    if (i < N) offs[i] = s[threadIdx.x] - v;
    if (threadIdx.x == 255) partials[blockIdx.x] = s[255];
}

__global__ void scan2_kernel(int* __restrict__ partials, int NB) {
    __shared__ int s[512];
    int v = (threadIdx.x < NB) ? partials[threadIdx.x] : 0;
    s[threadIdx.x] = v;
    __syncthreads();
    for (int d = 1; d < 512; d <<= 1) {
        int t = (threadIdx.x >= d) ? s[threadIdx.x - d] : 0;
        __syncthreads();
        s[threadIdx.x] += t;
        __syncthreads();
    }
    if (threadIdx.x < NB) partials[threadIdx.x] = s[threadIdx.x] - v;
}

__global__ void scan3_kernel(const int* __restrict__ cnt, int* __restrict__ offs,
                             const int* __restrict__ partials, int* __restrict__ cursor,
                             float* __restrict__ dinv, int N) {
    int i = blockIdx.x * 256 + threadIdx.x;
    if (i < N) {
        int o = offs[i] + partials[i >> 8];
        offs[i] = o;
        cursor[i] = o;
        dinv[i] = rsqrtf((float)(cnt[i] + 1));   // +1 self loop
    }
}

// ---------------- sort pass C: per-bucket CSR scatter ----------------

__launch_bounds__(256)
__global__ void csr_kernel(const unsigned long long* __restrict__ entries,
                           const int* __restrict__ gcnt,
                           int* __restrict__ cursor, int* __restrict__ sortedRow) {
    const int b = blockIdx.x;
    const int nb = gcnt[b];
    const unsigned long long* ep = entries + (size_t)b * BCAP;
    for (int i = threadIdx.x; i < nb; i += 256) {
        unsigned long long pk = ep[i];
        int c = (int)(pk >> 32);
        int r = (int)(pk & 0xFFFFFFFFu);
        int p = atomicAdd(&cursor[c], 1);
        sortedRow[p] = r;
    }
}

// ---------------- weight pre-transpose ----------------

__global__ void prep_w(const float* __restrict__ W0, const float* __restrict__ Wmu,
                       const float* __restrict__ Wsig,
                       unsigned short* __restrict__ W0h, unsigned short* __restrict__ W0l,
                       unsigned short* __restrict__ Wmsh, unsigned short* __restrict__ Wmsl) {
    int c = blockIdx.x;
    int k = threadIdx.x;
    if (c < 128) {                               // W0 [256][128] -> [128 cols][256 k]
        float v = W0[k * 128 + c];
        unsigned short h = f2bf(v);
        W0h[c * 256 + k] = h;
        W0l[c * 256 + k] = f2bf(v - bf2f(h));
    } else if (k < 128) {                        // Wmu|Wsig -> [256 cols][128 k]
        int c2 = c - 128;
        float v = (c2 < 128) ? Wmu[k * 128 + c2] : Wsig[k * 128 + (c2 - 128)];
        unsigned short h = f2bf(v);
        Wmsh[c2 * 128 + k] = h;
        Wmsl[c2 * 128 + k] = f2bf(v - bf2f(h));
    }
}

// ---------------- GEMM1: t0_bf16 = x @ W0 (3-term compensated, A=W swapped) -----------
// 512 thr = 8 waves x 16 nodes. 2x16KB double-buffered chunks [128 feat][64 k],
// 8 chunks = kh(2) x hl(2) x ks(2). D: col=node(lane&15), row=feature -> 8B t0 stores.

__launch_bounds__(512, 4)
__global__ void gemm1_mfma(const float* __restrict__ x,
                           const unsigned short* __restrict__ W0h,
                           const unsigned short* __restrict__ W0l,
                           char* __restrict__ outc) {
    __shared__ __align__(16) char Bs[2][16384];
    const int tid = threadIdx.x;
    const int wave = tid >> 6, lane = tid & 63;
    const int lrow = lane & 15;
    const int kb = (lane >> 4) * 16;            // byte offset of lane's k-group
    const int swz = (lrow & 7) << 4;
    const int koff0 = kb ^ swz, koff1 = (64 + kb) ^ swz;
    const int r0 = blockIdx.x * 128 + wave * 16;
    int rm = r0 + lrow; if (rm > N_NODES - 1) rm = N_NODES - 1;
    const float* ap = x + (size_t)rm * 256 + (lane >> 4) * 8;

    // staging addressing (constant per thread across chunks)
    const int colL = tid >> 3, k8 = (tid & 7) * 8;
    const int colH = colL + 64;
    const int dB0 = (colL * 128 + k8 * 2) ^ ((colL & 7) << 4);
    const int dB1 = (colH * 128 + k8 * 2) ^ ((colH & 7) << 4);

    // x kh0: load + split
    float4 xr[8];
    #pragma unroll
    for (int ki = 0; ki < 4; ki++) {
        xr[2 * ki]     = *(const float4*)(ap + ki * 32);
        xr[2 * ki + 1] = *(const float4*)(ap + ki * 32 + 4);
    }
    bf16x8 bh[4], bl[4];
    #pragma unroll
    for (int ki = 0; ki < 4; ki++) splitx(xr[2 * ki], xr[2 * ki + 1], bh[ki], bl[ki]);

    // stage chunk 0
    {
        const unsigned short* W = W0h;          // kh=0, hl=0, ks=0
        *(int4*)(Bs[0] + dB0) = *(const int4*)(W + colL * 256 + k8);
        *(int4*)(Bs[0] + dB1) = *(const int4*)(W + colH * 256 + k8);
    }
    __syncthreads();

    f32x4 acc[8] = {};
    #pragma unroll
    for (int c = 0; c < 8; c++) {
        const int ks = c & 1;
        // issue next-chunk weight loads
        int4 w0, w1;
        if (c < 7) {
            const int nc = c + 1;
            const unsigned short* W = (((nc >> 1) & 1) ? W0l : W0h)
                                      + (nc >> 2) * 128 + (nc & 1) * 64;
            w0 = *(const int4*)(W + colL * 256 + k8);
            w1 = *(const int4*)(W + colH * 256 + k8);
        }
        if (c == 3) {                           // prefetch x kh1 raw
            #pragma unroll
            for (int ki = 0; ki < 4; ki++) {
                xr[2 * ki]     = *(const float4*)(ap + 128 + ki * 32);
                xr[2 * ki + 1] = *(const float4*)(ap + 128 + ki * 32 + 4);
            }
        }
        if (c == 4) {                           // split x kh1
            #pragma unroll
            for (int ki = 0; ki < 4; ki++) splitx(xr[2 * ki], xr[2 * ki + 1], bh[ki], bl[ki]);
        }
        // MFMA on buf[c&1]
        const char* bufp = Bs[c & 1];
        const bool isHi = ((c >> 1) & 1) == 0;
        #pragma unroll
        for (int ki2 = 0; ki2 < 2; ki2++) {
            const int ki = ks * 2 + ki2;
            const int ko = ki2 ? koff1 : koff0;
            #pragma unroll
            for (int n = 0; n < 8; n++) {
                bf16x8 w = *(const bf16x8*)(bufp + (n * 16 + lrow) * 128 + ko);
                acc[n] = MFMA16(w, bh[ki], acc[n]);
                if (isHi) acc[n] = MFMA16(w, bl[ki], acc[n]);
            }
        }
        if (c < 7) {
            *(int4*)(Bs[(c + 1) & 1] + dB0) = w0;
            *(int4*)(Bs[(c + 1) & 1] + dB1) = w1;
            __syncthreads();
        }
    }

    // t0 store: lane owns node r0+lrow, features n*16+(lane>>4)*4 .. +3 -> 8B packed
    const int node = r0 + lrow;
    if (node < N_NODES) {
        char* dst = outc + (size_t)node * ROWB + 256;
        #pragma unroll
        for (int n = 0; n < 8; n++) {
            int f0 = n * 16 + (lane >> 4) * 4;
            ushort4 p = make_ushort4(f2bf(acc[n][0]), f2bf(acc[n][1]),
                                     f2bf(acc[n][2]), f2bf(acc[n][3]));
            *(ushort4*)(dst + f0 * 2) = p;
        }
    }
}

// ---------------- aggregation over bf16 rows (512B-strided), fp32 accumulate ------------

template <int EPI>
__launch_bounds__(256)
__global__ void agg_bf16(const char* __restrict__ srcBase, char* __restrict__ dstBase,
                         const int* __restrict__ offs, const int* __restrict__ cnt,
                         const int* __restrict__ sortedRow, const float* __restrict__ dinv,
                         const float* __restrict__ bias) {
    const int n = blockIdx.x * 4 + (threadIdx.x >> 6);
    const int lane = threadIdx.x & 63;
    const float dn = dinv[n];
    const char* srcLane = srcBase + (size_t)lane * 4;
    unsigned int u = *(const unsigned int*)(srcLane + (size_t)n * ROWB);
    const float ws = dn * dn;
    float acc0 = ws * bf_lo(u);
    float acc1 = ws * bf_hi(u);
    const int start = offs[n], num = cnt[n];

    for (int i = 0; i < num; i += 8) {
        int r[8];
        #pragma unroll
        for (int j = 0; j < 8; j++) {
            bool valid = (i + j) < num;
            int idx = start + (valid ? (i + j) : 0);
            int rr = sortedRow[idx];
            r[j] = valid ? rr : n;
        }
        unsigned int ue[8];
        #pragma unroll
        for (int j = 0; j < 8; j++)
            ue[j] = *(const unsigned int*)(srcLane + (size_t)r[j] * ROWB);
        float w[8];
        #pragma unroll
        for (int j = 0; j < 8; j++) {
            float wv = dn * dinv[r[j]];
            w[j] = ((i + j) < num) ? wv : 0.f;
        }
        #pragma unroll
        for (int j = 0; j < 8; j++) {
            acc0 = fmaf(w[j], bf_lo(ue[j]), acc0);
            acc1 = fmaf(w[j], bf_hi(ue[j]), acc1);
        }
    }

    if (EPI) {
        acc0 = fmaxf(acc0 + bias[2 * lane], 0.f);
        acc1 = fmaxf(acc1 + bias[2 * lane + 1], 0.f);
    }
    unsigned int o = (unsigned int)f2bf(acc0) | ((unsigned int)f2bf(acc1) << 16);
    *(unsigned int*)(dstBase + (size_t)n * ROWB + lane * 4) = o;
}

// ---------------- GEMM2: [mu|sigma] = t2 @ [Wmu|Wsig] (2-term, A=W swapped) ------------
// 8 chunks = half(2) x hl(2) x ks(2); mu epilogue after chunk 3 (float4 stores).

__launch_bounds__(512, 4)
__global__ void gemm2_mfma(const unsigned short* __restrict__ Bh,
                           const unsigned short* __restrict__ Bl,
                           const float* __restrict__ bmu, const float* __restrict__ bsig,
                           char* __restrict__ outc) {
    __shared__ __align__(16) char Bs[2][16384];
    const int tid = threadIdx.x;
    const int wave = tid >> 6, lane = tid & 63;
    const int lrow = lane & 15;
    const int kb = (lane >> 4) * 16;
    const int swz = (lrow & 7) << 4;
    const int koff0 = kb ^ swz, koff1 = (64 + kb) ^ swz;
    const int r0 = blockIdx.x * 128 + wave * 16;
    int rm = r0 + lrow; if (rm > N_NODES - 1) rm = N_NODES - 1;

    const int colL = tid >> 3, k8 = (tid & 7) * 8;
    const int colH = colL + 64;
    const int dB0 = (colL * 128 + k8 * 2) ^ ((colL & 7) << 4);
    const int dB1 = (colH * 128 + k8 * 2) ^ ((colH & 7) << 4);

    // prefetch B-operand: t2 node rows (bf16, 128 k)
    const char* apc = outc + (size_t)rm * ROWB + kb;
    bf16x8 b[4];
    #pragma unroll
    for (int ki = 0; ki < 4; ki++)
        b[ki] = *(const bf16x8*)(apc + ki * 64);

    // stage chunk 0 (mu, hi, ks0)
    *(int4*)(Bs[0] + dB0) = *(const int4*)(Bh + colL * 128 + k8);
    *(int4*)(Bs[0] + dB1) = *(const int4*)(Bh + colH * 128 + k8);
    __syncthreads();

    const int node = r0 + lrow;
    const bool ok = node < N_NODES;
    f32x4 acc[8] = {};

    #pragma unroll
    for (int c = 0; c < 8; c++) {
        const int ks = c & 1;
        int4 w0, w1;
        if (c < 7) {
            const int nc = c + 1;
            const unsigned short* W = (((nc >> 1) & 1) ? Bl : Bh)
                                      + (nc >> 2) * 16384 + (nc & 1) * 64;
            w0 = *(const int4*)(W + colL * 128 + k8);
            w1 = *(const int4*)(W + colH * 128 + k8);
        }
        const char* bufp = Bs[c & 1];
        #pragma unroll
        for (int ki2 = 0; ki2 < 2; ki2++) {
            const int ki = ks * 2 + ki2;
            const int ko = ki2 ? koff1 : koff0;
            #pragma unroll
            for (int n = 0; n < 8; n++) {
                bf16x8 w = *(const bf16x8*)(bufp + (n * 16 + lrow) * 128 + ko);
                acc[n] = MFMA16(w, b[ki], acc[n]);
            }
        }
        if (c == 3) {                           // mu epilogue, then reset acc
            if (ok) {
                char* dst = outc + (size_t)node * ROWB;
                #pragma unroll
                for (int n = 0; n < 8; n++) {
                    int f0 = n * 16 + (lane >> 4) * 4;
                    float4 bv = *(const float4*)(bmu + f0);
                    float4 o = make_float4(acc[n][0] + bv.x, acc[n][1] + bv.y,
                                           acc[n][2] + bv.z, acc[n][3] + bv.w);
                    *(float4*)(dst + f0 * 4) = o;
                }
            }
            #pragma unroll
            for (int n = 0; n < 8; n++) acc[n] = f32x4{0.f, 0.f, 0.f, 0.f};
        }
        if (c < 7) {
            *(int4*)(Bs[(c + 1) & 1] + dB0) = w0;
            *(int4*)(Bs[(c + 1) & 1] + dB1) = w1;
            __syncthreads();
        }
    }

    if (ok) {                                    // sigma epilogue
        char* dst = outc + HALFB + (size_t)node * ROWB;
        #pragma unroll
        for (int n = 0; n < 8; n++) {
            int f0 = n * 16 + (lane >> 4) * 4;
            float4 bv = *(const float4*)(bsig + f0);
            float t[4];
            #pragma unroll
            for (int q = 0; q < 4; q++) {
                float xv = acc[n][q] + ((const float*)&bv)[q];
                t[q] = fmaxf(xv, 0.f) + log1pf(expf(-fabsf(xv))) + 1e-7f;
            }
            *(float4*)(dst + f0 * 4) = make_float4(t[0], t[1], t[2], t[3]);
        }
    }
}

// ---------------- launch ----------------

extern "C" void kernel_launch(void* const* d_in, const int* in_sizes, int n_in,
                              void* d_out, int out_size, void* d_ws, size_t ws_size,
                              hipStream_t stream) {
    const float* x    = (const float*)d_in[0];
    const int*   ei   = (const int*)d_in[1];
    const int*   row  = ei;
    const int*   col  = ei + N_EDGES;
    const float* W0   = (const float*)d_in[2];
    const float* b0   = (const float*)d_in[3];
    const float* Wmu  = (const float*)d_in[4];
    const float* bmu  = (const float*)d_in[5];
    const float* Wsig = (const float*)d_in[6];
    const float* bsig = (const float*)d_in[7];
    char* outc = (char*)d_out;

    unsigned short* W0h  = (unsigned short*)d_ws;       // 128*256
    unsigned short* W0l  = W0h + 32768;
    unsigned short* Wmsh = W0l + 32768;                 // 256*128
    unsigned short* Wmsl = Wmsh + 32768;
    int*   cnt       = (int*)(Wmsl + 32768);
    int*   gcur      = cnt + N_NODES;                   // NBKT ints (memset with cnt)
    int*   offs      = gcur + NBKT;
    int*   cursor    = offs + N_NODES;
    float* dinvp     = (float*)(cursor + N_NODES);
    int*   sortedRow = (int*)(dinvp + N_NODES);
    int*   partials  = sortedRow + N_EDGES;             // 512 ints

    unsigned long long* entries = (unsigned long long*)(outc + HALFB);

    const int NB = (N_NODES + 255) / 256;               // 391

    hipMemsetAsync(cnt, 0, (N_NODES + NBKT) * sizeof(int), stream);
    prep_w<<<384, 256, 0, stream>>>(W0, Wmu, Wsig, W0h, W0l, Wmsh, Wmsl);
    bin_kernel<<<(N_EDGES + 4095) / 4096, 256, 0, stream>>>(row, col, cnt, gcur, entries);
    scan1_kernel<<<NB, 256, 0, stream>>>(cnt, offs, partials, N_NODES);
    scan2_kernel<<<1, 512, 0, stream>>>(partials, NB);
    scan3_kernel<<<NB, 256, 0, stream>>>(cnt, offs, partials, cursor, dinvp, N_NODES);
    csr_kernel<<<NBKT, 256, 0, stream>>>(entries, gcur, cursor, sortedRow);

    gemm1_mfma<<<(N_NODES + 127) / 128, 512, 0, stream>>>(x, W0h, W0l, outc);
    agg_bf16<1><<<N_NODES / 4, 256, 0, stream>>>(outc + 256, outc + HALFB,
                                                 offs, cnt, sortedRow, dinvp, b0);
    agg_bf16<0><<<N_NODES / 4, 256, 0, stream>>>(outc + HALFB, outc,
                                                 offs, cnt, sortedRow, dinvp, nullptr);
    gemm2_mfma<<<(N_NODES + 127) / 128, 512, 0, stream>>>(Wmsh, Wmsl, bmu, bsig, outc);
}

// Round 8
// 312.998 us; speedup vs baseline: 2.6342x; 1.1856x over previous
//
#include <hip/hip_runtime.h>
#include <math.h>

#define N_NODES 100000
#define N_EDGES 1600000
#define ROWB    512                 // bytes per row slot in d_out
#define HALFB   51200000ull         // byte offset of second output (sigma half)
#define NBKT    196                 // sort buckets (512 dst nodes each)
#define BSH     9
#define BCAP    10240               // entries per bucket (mean 8192, >20 sigma margin)
#define EPB     1024                // edges per bin block

typedef float  f32x4  __attribute__((ext_vector_type(4)));
typedef __bf16 bf16x8 __attribute__((ext_vector_type(8)));
typedef short  s16x8  __attribute__((ext_vector_type(8)));
typedef unsigned long long u64;

__device__ __forceinline__ unsigned short f2bf(float f) {
    unsigned int u = __builtin_bit_cast(unsigned int, f);
    u += 0x7FFFu + ((u >> 16) & 1u);          // RNE
    return (unsigned short)(u >> 16);
}
__device__ __forceinline__ float bf2f(unsigned short h) {
    unsigned int u = ((unsigned int)h) << 16;
    return __builtin_bit_cast(float, u);
}
__device__ __forceinline__ float bf_lo(unsigned int u) {
    return __builtin_bit_cast(float, u << 16);
}
__device__ __forceinline__ float bf_hi(unsigned int u) {
    return __builtin_bit_cast(float, u & 0xFFFF0000u);
}
__device__ __forceinline__ void splitx(const float4& a, const float4& b,
                                       bf16x8& hi, bf16x8& lo) {
    float v[8] = {a.x, a.y, a.z, a.w, b.x, b.y, b.z, b.w};
    s16x8 hh, ll;
    #pragma unroll
    for (int j = 0; j < 8; j++) {
        unsigned short hb = f2bf(v[j]);
        hh[j] = (short)hb;
        ll[j] = (short)f2bf(v[j] - bf2f(hb));
    }
    hi = __builtin_bit_cast(bf16x8, hh);
    lo = __builtin_bit_cast(bf16x8, ll);
}

#define MFMA16(a, b, c) __builtin_amdgcn_mfma_f32_16x16x32_bf16((a), (b), (c), 0, 0, 0)

// ---------------- sort pass B: bucket-binning (no degree atomics) ----------------
// 1563 blocks x 1024 edges. LDS histogram -> one global atomic per (block,bucket) ->
// dense per-bucket append of packed (col,row).

__launch_bounds__(256)
__global__ void bin_kernel(const int* __restrict__ row, const int* __restrict__ col,
                           int* __restrict__ gcur, u64* __restrict__ entries) {
    __shared__ int hist[NBKT], base[NBKT], cur[NBKT];
    const int tid = threadIdx.x;
    for (int i = tid; i < NBKT; i += 256) { hist[i] = 0; cur[i] = 0; }
    __syncthreads();
    const int e0 = blockIdx.x * EPB;
    int cols[4];
    #pragma unroll
    for (int it = 0; it < 4; it++) {
        int e = e0 + it * 256 + tid;
        int c = (e < N_EDGES) ? col[e] : -1;
        cols[it] = c;
        if (c >= 0) atomicAdd(&hist[c >> BSH], 1);
    }
    __syncthreads();
    for (int i = tid; i < NBKT; i += 256)
        base[i] = atomicAdd(&gcur[i], hist[i]);
    __syncthreads();
    #pragma unroll
    for (int it = 0; it < 4; it++) {
        int e = e0 + it * 256 + tid;
        int c = cols[it];
        if (c >= 0) {
            int b = c >> BSH;
            int r = atomicAdd(&cur[b], 1);
            entries[(size_t)b * BCAP + base[b] + r] =
                ((u64)(unsigned)c << 32) | (unsigned)row[e];
        }
    }
}

// ---------------- bucket-base scan (196 values, 1 block) ----------------

__global__ void bktscan_kernel(const int* __restrict__ gcur, int* __restrict__ bktBase) {
    __shared__ int s[256];
    const int tid = threadIdx.x;
    int v = (tid < NBKT) ? gcur[tid] : 0;
    s[tid] = v;
    __syncthreads();
    for (int d = 1; d < 256; d <<= 1) {
        int t = (tid >= d) ? s[tid - d] : 0;
        __syncthreads();
        s[tid] += t;
        __syncthreads();
    }
    if (tid < NBKT) bktBase[tid] = s[tid] - v;
}

// ---------------- sort pass C: per-bucket histogram + scan + scatter ----------------
// One block per bucket (512 nodes). Writes cnt/offs/dinv directly (no memset needed),
// scatters with LDS cursors into the bucket's contiguous sortedRow window.

__launch_bounds__(256)
__global__ void csr_kernel(const u64* __restrict__ entries, const int* __restrict__ gcur,
                           const int* __restrict__ bktBase,
                           int* __restrict__ cnt, int* __restrict__ offs,
                           float* __restrict__ dinv, int* __restrict__ sortedRow) {
    __shared__ int lcnt[512], sA[512], sB[512], lcur[512];
    const int b = blockIdx.x, tid = threadIdx.x;
    const int n0 = b << BSH;
    lcnt[tid] = 0; lcnt[tid + 256] = 0;
    __syncthreads();
    const int nb = gcur[b], base = bktBase[b];
    const u64* ep = entries + (size_t)b * BCAP;
    for (int i = tid; i < nb; i += 256)
        atomicAdd(&lcnt[(int)(ep[i] >> 32) - n0], 1);
    __syncthreads();
    sA[tid] = lcnt[tid]; sA[tid + 256] = lcnt[tid + 256];
    __syncthreads();
    int* src = sA; int* dst = sB;
    for (int d = 1; d < 512; d <<= 1) {
        #pragma unroll
        for (int k = tid; k < 512; k += 256)
            dst[k] = src[k] + ((k >= d) ? src[k - d] : 0);
        __syncthreads();
        int* t = src; src = dst; dst = t;
    }
    #pragma unroll
    for (int k = tid; k < 512; k += 256) {
        int excl = src[k] - lcnt[k];
        lcur[k] = excl;
        int node = n0 + k;
        if (node < N_NODES) {
            offs[node] = base + excl;
            cnt[node]  = lcnt[k];
            dinv[node] = rsqrtf((float)(lcnt[k] + 1));   // +1 self loop
        }
    }
    __syncthreads();
    for (int i = tid; i < nb; i += 256) {
        u64 pk = ep[i];
        int local = (int)(pk >> 32) - n0;
        int p = base + atomicAdd(&lcur[local], 1);
        sortedRow[p] = (int)(pk & 0xFFFFFFFFu);
    }
}

// ---------------- weight pre-transpose ----------------

__global__ void prep_w(const float* __restrict__ W0, const float* __restrict__ Wmu,
                       const float* __restrict__ Wsig,
                       unsigned short* __restrict__ W0h, unsigned short* __restrict__ W0l,
                       unsigned short* __restrict__ Wmsh, unsigned short* __restrict__ Wmsl) {
    int c = blockIdx.x;
    int k = threadIdx.x;
    if (c < 128) {                               // W0 [256][128] -> [128 cols][256 k]
        float v = W0[k * 128 + c];
        unsigned short h = f2bf(v);
        W0h[c * 256 + k] = h;
        W0l[c * 256 + k] = f2bf(v - bf2f(h));
    } else if (k < 128) {                        // Wmu|Wsig -> [256 cols][128 k]
        int c2 = c - 128;
        float v = (c2 < 128) ? Wmu[k * 128 + c2] : Wsig[k * 128 + (c2 - 128)];
        unsigned short h = f2bf(v);
        Wmsh[c2 * 128 + k] = h;
        Wmsl[c2 * 128 + k] = f2bf(v - bf2f(h));
    }
}

// ---------------- GEMM1: t0_bf16 = x @ W0 (3-term compensated, A=W swapped) -----------

__launch_bounds__(512, 4)
__global__ void gemm1_mfma(const float* __restrict__ x,
                           const unsigned short* __restrict__ W0h,
                           const unsigned short* __restrict__ W0l,
                           char* __restrict__ outc) {
    __shared__ __align__(16) char Bs[2][16384];
    const int tid = threadIdx.x;
    const int wave = tid >> 6, lane = tid & 63;
    const int lrow = lane & 15;
    const int kb = (lane >> 4) * 16;
    const int swz = (lrow & 7) << 4;
    const int koff0 = kb ^ swz, koff1 = (64 + kb) ^ swz;
    const int r0 = blockIdx.x * 128 + wave * 16;
    int rm = r0 + lrow; if (rm > N_NODES - 1) rm = N_NODES - 1;
    const float* ap = x + (size_t)rm * 256 + (lane >> 4) * 8;

    const int colL = tid >> 3, k8 = (tid & 7) * 8;
    const int colH = colL + 64;
    const int dB0 = (colL * 128 + k8 * 2) ^ ((colL & 7) << 4);
    const int dB1 = (colH * 128 + k8 * 2) ^ ((colH & 7) << 4);

    float4 xr[8];
    #pragma unroll
    for (int ki = 0; ki < 4; ki++) {
        xr[2 * ki]     = *(const float4*)(ap + ki * 32);
        xr[2 * ki + 1] = *(const float4*)(ap + ki * 32 + 4);
    }
    bf16x8 bh[4], bl[4];
    #pragma unroll
    for (int ki = 0; ki < 4; ki++) splitx(xr[2 * ki], xr[2 * ki + 1], bh[ki], bl[ki]);

    {
        const unsigned short* W = W0h;
        *(int4*)(Bs[0] + dB0) = *(const int4*)(W + colL * 256 + k8);
        *(int4*)(Bs[0] + dB1) = *(const int4*)(W + colH * 256 + k8);
    }
    __syncthreads();

    f32x4 acc[8] = {};
    #pragma unroll
    for (int c = 0; c < 8; c++) {
        const int ks = c & 1;
        int4 w0, w1;
        if (c < 7) {
            const int nc = c + 1;
            const unsigned short* W = (((nc >> 1) & 1) ? W0l : W0h)
                                      + (nc >> 2) * 128 + (nc & 1) * 64;
            w0 = *(const int4*)(W + colL * 256 + k8);
            w1 = *(const int4*)(W + colH * 256 + k8);
        }
        if (c == 3) {
            #pragma unroll
            for (int ki = 0; ki < 4; ki++) {
                xr[2 * ki]     = *(const float4*)(ap + 128 + ki * 32);
                xr[2 * ki + 1] = *(const float4*)(ap + 128 + ki * 32 + 4);
            }
        }
        if (c == 4) {
            #pragma unroll
            for (int ki = 0; ki < 4; ki++) splitx(xr[2 * ki], xr[2 * ki + 1], bh[ki], bl[ki]);
        }
        const char* bufp = Bs[c & 1];
        const bool isHi = ((c >> 1) & 1) == 0;
        #pragma unroll
        for (int ki2 = 0; ki2 < 2; ki2++) {
            const int ki = ks * 2 + ki2;
            const int ko = ki2 ? koff1 : koff0;
            #pragma unroll
            for (int n = 0; n < 8; n++) {
                bf16x8 w = *(const bf16x8*)(bufp + (n * 16 + lrow) * 128 + ko);
                acc[n] = MFMA16(w, bh[ki], acc[n]);
                if (isHi) acc[n] = MFMA16(w, bl[ki], acc[n]);
            }
        }
        if (c < 7) {
            *(int4*)(Bs[(c + 1) & 1] + dB0) = w0;
            *(int4*)(Bs[(c + 1) & 1] + dB1) = w1;
            __syncthreads();
        }
    }

    const int node = r0 + lrow;
    if (node < N_NODES) {
        char* dst = outc + (size_t)node * ROWB + 256;
        #pragma unroll
        for (int n = 0; n < 8; n++) {
            int f0 = n * 16 + (lane >> 4) * 4;
            ushort4 p = make_ushort4(f2bf(acc[n][0]), f2bf(acc[n][1]),
                                     f2bf(acc[n][2]), f2bf(acc[n][3]));
            *(ushort4*)(dst + f0 * 2) = p;
        }
    }
}

// ---------------- aggregation over bf16 rows (512B-strided), fp32 accumulate ------------

template <int EPI>
__launch_bounds__(256)
__global__ void agg_bf16(const char* __restrict__ srcBase, char* __restrict__ dstBase,
                         const int* __restrict__ offs, const int* __restrict__ cnt,
                         const int* __restrict__ sortedRow, const float* __restrict__ dinv,
                         const float* __restrict__ bias) {
    const int n = blockIdx.x * 4 + (threadIdx.x >> 6);
    const int lane = threadIdx.x & 63;
    const float dn = dinv[n];
    const char* srcLane = srcBase + (size_t)lane * 4;
    unsigned int u = *(const unsigned int*)(srcLane + (size_t)n * ROWB);
    const float ws = dn * dn;
    float acc0 = ws * bf_lo(u);
    float acc1 = ws * bf_hi(u);
    const int start = offs[n], num = cnt[n];

    for (int i = 0; i < num; i += 8) {
        int r[8];
        #pragma unroll
        for (int j = 0; j < 8; j++) {
            bool valid = (i + j) < num;
            int idx = start + (valid ? (i + j) : 0);
            int rr = sortedRow[idx];
            r[j] = valid ? rr : n;
        }
        unsigned int ue[8];
        #pragma unroll
        for (int j = 0; j < 8; j++)
            ue[j] = *(const unsigned int*)(srcLane + (size_t)r[j] * ROWB);
        float w[8];
        #pragma unroll
        for (int j = 0; j < 8; j++) {
            float wv = dn * dinv[r[j]];
            w[j] = ((i + j) < num) ? wv : 0.f;
        }
        #pragma unroll
        for (int j = 0; j < 8; j++) {
            acc0 = fmaf(w[j], bf_lo(ue[j]), acc0);
            acc1 = fmaf(w[j], bf_hi(ue[j]), acc1);
        }
    }

    if (EPI) {
        acc0 = fmaxf(acc0 + bias[2 * lane], 0.f);
        acc1 = fmaxf(acc1 + bias[2 * lane + 1], 0.f);
    }
    unsigned int o = (unsigned int)f2bf(acc0) | ((unsigned int)f2bf(acc1) << 16);
    *(unsigned int*)(dstBase + (size_t)n * ROWB + lane * 4) = o;
}

// ---------------- GEMM2: [mu|sigma] = t2 @ [Wmu|Wsig] (2-term, A=W swapped) ------------

__launch_bounds__(512, 4)
__global__ void gemm2_mfma(const unsigned short* __restrict__ Bh,
                           const unsigned short* __restrict__ Bl,
                           const float* __restrict__ bmu, const float* __restrict__ bsig,
                           char* __restrict__ outc) {
    __shared__ __align__(16) char Bs[2][16384];
    const int tid = threadIdx.x;
    const int wave = tid >> 6, lane = tid & 63;
    const int lrow = lane & 15;
    const int kb = (lane >> 4) * 16;
    const int swz = (lrow & 7) << 4;
    const int koff0 = kb ^ swz, koff1 = (64 + kb) ^ swz;
    const int r0 = blockIdx.x * 128 + wave * 16;
    int rm = r0 + lrow; if (rm > N_NODES - 1) rm = N_NODES - 1;

    const int colL = tid >> 3, k8 = (tid & 7) * 8;
    const int colH = colL + 64;
    const int dB0 = (colL * 128 + k8 * 2) ^ ((colL & 7) << 4);
    const int dB1 = (colH * 128 + k8 * 2) ^ ((colH & 7) << 4);

    const char* apc = outc + (size_t)rm * ROWB + kb;
    bf16x8 b[4];
    #pragma unroll
    for (int ki = 0; ki < 4; ki++)
        b[ki] = *(const bf16x8*)(apc + ki * 64);

    *(int4*)(Bs[0] + dB0) = *(const int4*)(Bh + colL * 128 + k8);
    *(int4*)(Bs[0] + dB1) = *(const int4*)(Bh + colH * 128 + k8);
    __syncthreads();

    const int node = r0 + lrow;
    const bool ok = node < N_NODES;
    f32x4 acc[8] = {};

    #pragma unroll
    for (int c = 0; c < 8; c++) {
        const int ks = c & 1;
        int4 w0, w1;
        if (c < 7) {
            const int nc = c + 1;
            const unsigned short* W = (((nc >> 1) & 1) ? Bl : Bh)
                                      + (nc >> 2) * 16384 + (nc & 1) * 64;
            w0 = *(const int4*)(W + colL * 128 + k8);
            w1 = *(const int4*)(W + colH * 128 + k8);
        }
        const char* bufp = Bs[c & 1];
        #pragma unroll
        for (int ki2 = 0; ki2 < 2; ki2++) {
            const int ki = ks * 2 + ki2;
            const int ko = ki2 ? koff1 : koff0;
            #pragma unroll
            for (int n = 0; n < 8; n++) {
                bf16x8 w = *(const bf16x8*)(bufp + (n * 16 + lrow) * 128 + ko);
                acc[n] = MFMA16(w, b[ki], acc[n]);
            }
        }
        if (c == 3) {
            if (ok) {
                char* dst = outc + (size_t)node * ROWB;
                #pragma unroll
                for (int n = 0; n < 8; n++) {
                    int f0 = n * 16 + (lane >> 4) * 4;
                    float4 bv = *(const float4*)(bmu + f0);
                    float4 o = make_float4(acc[n][0] + bv.x, acc[n][1] + bv.y,
                                           acc[n][2] + bv.z, acc[n][3] + bv.w);
                    *(float4*)(dst + f0 * 4) = o;
                }
            }
            #pragma unroll
            for (int n = 0; n < 8; n++) acc[n] = f32x4{0.f, 0.f, 0.f, 0.f};
        }
        if (c < 7) {
            *(int4*)(Bs[(c + 1) & 1] + dB0) = w0;
            *(int4*)(Bs[(c + 1) & 1] + dB1) = w1;
            __syncthreads();
        }
    }

    if (ok) {
        char* dst = outc + HALFB + (size_t)node * ROWB;
        #pragma unroll
        for (int n = 0; n < 8; n++) {
            int f0 = n * 16 + (lane >> 4) * 4;
            float4 bv = *(const float4*)(bsig + f0);
            float t[4];
            #pragma unroll
            for (int q = 0; q < 4; q++) {
                float xv = acc[n][q] + ((const float*)&bv)[q];
                t[q] = fmaxf(xv, 0.f) + log1pf(expf(-fabsf(xv))) + 1e-7f;
            }
            *(float4*)(dst + f0 * 4) = make_float4(t[0], t[1], t[2], t[3]);
        }
    }
}

// ---------------- launch ----------------

extern "C" void kernel_launch(void* const* d_in, const int* in_sizes, int n_in,
                              void* d_out, int out_size, void* d_ws, size_t ws_size,
                              hipStream_t stream) {
    const float* x    = (const float*)d_in[0];
    const int*   ei   = (const int*)d_in[1];
    const int*   row  = ei;
    const int*   col  = ei + N_EDGES;
    const float* W0   = (const float*)d_in[2];
    const float* b0   = (const float*)d_in[3];
    const float* Wmu  = (const float*)d_in[4];
    const float* bmu  = (const float*)d_in[5];
    const float* Wsig = (const float*)d_in[6];
    const float* bsig = (const float*)d_in[7];
    char* outc = (char*)d_out;

    unsigned short* W0h  = (unsigned short*)d_ws;       // 128*256
    unsigned short* W0l  = W0h + 32768;
    unsigned short* Wmsh = W0l + 32768;                 // 256*128
    unsigned short* Wmsl = Wmsh + 32768;
    int*   cnt       = (int*)(Wmsl + 32768);
    int*   gcur      = cnt + N_NODES;                   // NBKT ints (memset)
    int*   bktBase   = gcur + NBKT;                     // NBKT ints
    int*   offs      = bktBase + NBKT;
    float* dinvp     = (float*)(offs + N_NODES);
    int*   sortedRow = (int*)(dinvp + N_NODES);

    u64* entries = (u64*)(outc + HALFB);                // sigma half scratch

    hipMemsetAsync(gcur, 0, NBKT * sizeof(int), stream);
    prep_w<<<384, 256, 0, stream>>>(W0, Wmu, Wsig, W0h, W0l, Wmsh, Wmsl);
    bin_kernel<<<(N_EDGES + EPB - 1) / EPB, 256, 0, stream>>>(row, col, gcur, entries);
    bktscan_kernel<<<1, 256, 0, stream>>>(gcur, bktBase);
    csr_kernel<<<NBKT, 256, 0, stream>>>(entries, gcur, bktBase, cnt, offs, dinvp, sortedRow);

    gemm1_mfma<<<(N_NODES + 127) / 128, 512, 0, stream>>>(x, W0h, W0l, outc);
    agg_bf16<1><<<N_NODES / 4, 256, 0, stream>>>(outc + 256, outc + HALFB,
                                                 offs, cnt, sortedRow, dinvp, b0);
    agg_bf16<0><<<N_NODES / 4, 256, 0, stream>>>(outc + HALFB, outc,
                                                 offs, cnt, sortedRow, dinvp, nullptr);
    gemm2_mfma<<<(N_NODES + 127) / 128, 512, 0, stream>>>(Wmsh, Wmsl, bmu, bsig, outc);
}